// Round 5
// baseline (2451.511 us; speedup 1.0000x reference)
//
#include <hip/hip_runtime.h>
#include <hip/hip_bf16.h>

#define N_NODES 100000
#define N_EDGES 3200000
#define IN_DIM  256
#define OUT_DIM 64
#define NB_SCAN ((N_NODES + 255) / 256)   // 391
#define NBUK 8
#define BUK_RANGE 12500                   // 8 * 12500 == 100000 exactly
#define EDGE_GRID 2048                    // degree_hist and binfill MUST match

typedef __attribute__((ext_vector_type(8))) short short8;
typedef __attribute__((ext_vector_type(4))) float float4v;

// ---------------------------------------------------------------------------
// Kernel 1: detect edge_index dtype (sampled). int64 (values < 2^31) -> every
// odd 32-bit word is 0. int32 -> odd words are node ids, nonzero w.h.p.
// (P[2048 uniform ids in 0..1e5 are all 0] ~ 1e-10238). flag=1 -> int32.
// ---------------------------------------------------------------------------
__global__ void detect_dtype_kernel(const int* __restrict__ ei32, int* __restrict__ flag) {
    int i = threadIdx.x;
    int found = 0;
    for (int w = 2 * i + 1; w < 8192; w += 512)
        found |= (ei32[w] != 0);
    if (found) atomicOr(flag, 1);
}

__device__ __forceinline__ void load_edge(const void* ei, int e, bool is64, int& s, int& d) {
    if (is64) {
        const long long* e64 = (const long long*)ei;
        s = (int)e64[e];
        d = (int)e64[N_EDGES + e];
    } else {
        const int* e32 = (const int*)ei;
        s = e32[e];
        d = e32[N_EDGES + e];
    }
}

// ---------------------------------------------------------------------------
// Kernel 2: degree count into per-XCD-class private copies (atomics stay in
// one XCD's L2) + exact per-(class,bucket) edge histogram for binfill bases.
// Grid/edge mapping MUST be identical to binfill_kernel.
// ---------------------------------------------------------------------------
__global__ __launch_bounds__(256) void degree_hist_kernel(
    const void* __restrict__ ei, const int* __restrict__ flag,
    int* __restrict__ deg_priv, int* __restrict__ hist2) {
    __shared__ int lhist[NBUK];
    bool is64 = (*flag == 0);
    int tid = threadIdx.x;
    if (tid < NBUK) lhist[tid] = 0;
    __syncthreads();
    int c = blockIdx.x & 7;
    int* dp = deg_priv + c * N_NODES;
    int i = blockIdx.x * 256 + tid;
    int stride = 256 * EDGE_GRID;
    for (int e = i; e < N_EDGES; e += stride) {
        int s, d;
        load_edge(ei, e, is64, s, d);
        atomicAdd(&dp[d], 1);
        atomicAdd(&lhist[d / BUK_RANGE], 1);
    }
    __syncthreads();
    if (tid < NBUK) atomicAdd(&hist2[c * NBUK + tid], lhist[tid]);
}

// ---------------------------------------------------------------------------
// Kernels 3a/3b/3c: hierarchical exclusive scan -> offs/cursor/isq/dinv.
// scan1 also reduces the 8 private degree copies into deg.
// ---------------------------------------------------------------------------
__global__ __launch_bounds__(256) void scan1_kernel(const int* __restrict__ deg_priv,
                                                    int* __restrict__ deg,
                                                    int* __restrict__ bsum) {
    __shared__ int red[256];
    int tid = threadIdx.x;
    int i = blockIdx.x * 256 + tid;
    int v = 0;
    if (i < N_NODES) {
        #pragma unroll
        for (int c = 0; c < 8; ++c) v += deg_priv[c * N_NODES + i];
        deg[i] = v;
    }
    red[tid] = v;
    __syncthreads();
    #pragma unroll
    for (int off = 128; off > 0; off >>= 1) {
        if (tid < off) red[tid] += red[tid + off];
        __syncthreads();
    }
    if (tid == 0) bsum[blockIdx.x] = red[0];
}

__global__ __launch_bounds__(512) void scan2_kernel(int* __restrict__ bsum) {
    __shared__ int sh[512];
    int tid = threadIdx.x;
    int v = (tid < NB_SCAN) ? bsum[tid] : 0;
    sh[tid] = v;
    __syncthreads();
    int val = v;
    #pragma unroll
    for (int off = 1; off < 512; off <<= 1) {
        int t = (tid >= off) ? sh[tid - off] : 0;
        __syncthreads();
        val += t;
        sh[tid] = val;
        __syncthreads();
    }
    if (tid < NB_SCAN) bsum[tid] = val - v;   // exclusive block prefix
}

__global__ __launch_bounds__(256) void scan3_kernel(const int* __restrict__ deg,
                                                    const int* __restrict__ bsum,
                                                    int* __restrict__ offs,
                                                    int* __restrict__ cursor,
                                                    float* __restrict__ isq,
                                                    float* __restrict__ dinv) {
    __shared__ int sh[256];
    int tid = threadIdx.x;
    int i = blockIdx.x * 256 + tid;
    int d = (i < N_NODES) ? deg[i] : 0;
    sh[tid] = d;
    __syncthreads();
    int val = d;
    #pragma unroll
    for (int off = 1; off < 256; off <<= 1) {
        int t = (tid >= off) ? sh[tid - off] : 0;
        __syncthreads();
        val += t;
        sh[tid] = val;
        __syncthreads();
    }
    int ex = bsum[blockIdx.x] + val - d;      // exclusive prefix for node i
    if (i < N_NODES) {
        offs[i] = ex;
        cursor[i] = ex;
        float dr = (float)(d + 1);
        isq[i] = rsqrtf(dr);
        dinv[i] = 1.0f / dr;
    }
    if (i == 0) offs[N_NODES] = N_EDGES;      // total degree == E by construction
}

// ---------------------------------------------------------------------------
// Kernel 3d: per-(class,bucket) append bases. bukcur2[c][b] = offs[b*RANGE] +
// sum_{c'<c} hist2[c'][b]. Bases exactly partition each bucket's CSR range.
// ---------------------------------------------------------------------------
__global__ void bukbase_kernel(const int* __restrict__ offs, const int* __restrict__ hist2,
                               int* __restrict__ bukcur2) {
    int t = threadIdx.x;          // 64 threads: c = t>>3, b = t&7
    if (t < 64) {
        int c = t >> 3, b = t & 7;
        int base = offs[b * BUK_RANGE];
        for (int cc = 0; cc < c; ++cc) base += hist2[cc * NBUK + b];
        bukcur2[t] = base;
    }
}

// ---------------------------------------------------------------------------
// Kernel 4a: binned append. Wave-aggregated: per wave per bucket, one atomic
// reserves a contiguous run; records written as ~64B bursts. Atomics for
// class c are touched only by blocks with blockIdx%8==c (one XCD's L2).
// ---------------------------------------------------------------------------
__global__ __launch_bounds__(256) void binfill_kernel(
    const void* __restrict__ ei, const int* __restrict__ flag,
    int* __restrict__ bukcur2, uint2* __restrict__ bukbuf) {
    bool is64 = (*flag == 0);
    int c = blockIdx.x & 7;
    int lane = threadIdx.x & 63;
    int i = blockIdx.x * 256 + threadIdx.x;
    int stride = 256 * EDGE_GRID;
    for (int e = i; e < N_EDGES; e += stride) {
        int s, d;
        load_edge(ei, e, is64, s, d);
        int b = d / BUK_RANGE;
        #pragma unroll
        for (int bb = 0; bb < NBUK; ++bb) {
            unsigned long long mask = __ballot(b == bb);
            int cnt = __popcll(mask);
            if (cnt == 0) continue;
            int leader = __ffsll((long long)mask) - 1;
            int pos = 0;
            if (lane == leader) pos = atomicAdd(&bukcur2[c * NBUK + bb], cnt);
            pos = __shfl(pos, leader);
            if (b == bb) {
                int rank = __popcll(mask & ((1ull << lane) - 1ull));
                bukbuf[pos + rank] = make_uint2((unsigned)s, (unsigned)d);
            }
        }
    }
}

// ---------------------------------------------------------------------------
// Kernel 4b: XCD-local scatter. Block handles bucket blockIdx%8 only: cursor
// window (50KB) and csr window (~1.6MB) both live in that XCD's L2.
// ---------------------------------------------------------------------------
__global__ __launch_bounds__(256) void scatter_kernel(
    const uint2* __restrict__ bukbuf, const int* __restrict__ offs,
    int* __restrict__ cursor, unsigned int* __restrict__ csr) {
    int b = blockIdx.x & 7;
    int nb = gridDim.x >> 3;
    int bi = blockIdx.x >> 3;
    int lo = offs[b * BUK_RANGE];
    int hi = offs[(b + 1) * BUK_RANGE];       // offs[N]==E handles b==7
    for (int j = lo + bi * 256 + threadIdx.x; j < hi; j += nb * 256) {
        uint2 r = bukbuf[j];
        int pos = atomicAdd(&cursor[(int)r.y], 1);
        csr[pos] = r.x;
    }
}

// ---------------------------------------------------------------------------
// Kernel 5: prep weights: Wt[c][k] = bf16(W[k][c]), bias vector biasAll[192].
// ---------------------------------------------------------------------------
__global__ void prep_w_kernel(const float* __restrict__ Whp, const float* __restrict__ bhp,
                              const float* __restrict__ Wlp, const float* __restrict__ blp,
                              const float* __restrict__ Wi,  const float* __restrict__ bi,
                              __hip_bfloat16* __restrict__ Wt, float* __restrict__ biasAll) {
    int c = blockIdx.x;      // 0..191
    int k = threadIdx.x;     // 0..255
    const float* W = (c < 64) ? Whp : (c < 128) ? Wlp : Wi;
    int cl = c & 63;
    Wt[c * 256 + k] = __float2bfloat16(W[k * 64 + cl]);
    if (k == 0) {
        const float* b = (c < 64) ? bhp : (c < 128) ? blp : bi;
        biasAll[c] = b[cl];
    }
}

// ---------------------------------------------------------------------------
// Kernel 6: bf16 MFMA GEMM. Block = 256 threads (4 waves), 64 nodes.
// Outputs only the bf16 tables: hg (hp,lp packed bf16x2) + hgi (i bf16).
// ---------------------------------------------------------------------------
__global__ __launch_bounds__(256) void gemm_kernel(
    const float* __restrict__ x,
    const __hip_bfloat16* __restrict__ Wt,
    const float* __restrict__ biasAll,
    unsigned int* __restrict__ hg, unsigned short* __restrict__ hgi) {

    __shared__ __align__(16) __hip_bfloat16 xs[64][264];

    const int tid = threadIdx.x;
    const int node0 = blockIdx.x * 64;
    const int w = tid >> 6;
    const int lane = tid & 63;
    const int cl = lane & 15;
    const int kh = lane >> 4;

    // --- B fragments: Wt[col][ks*32 + kh*8 .. +8], col = 16w + 64s + cl ---
    short8 B[3][8];
    #pragma unroll
    for (int s = 0; s < 3; ++s) {
        const __hip_bfloat16* wp = Wt + (16 * w + 64 * s + cl) * 256 + kh * 8;
        #pragma unroll
        for (int ks = 0; ks < 8; ++ks)
            B[s][ks] = *(const short8*)(wp + ks * 32);
    }

    // --- stage x tile (64 x 256 f32 -> bf16 LDS), coalesced 16B/lane ---
    #pragma unroll
    for (int j = 0; j < 16; ++j) {
        int f = j * 1024 + tid * 4;          // flat float index in tile
        int rr = f >> 8, cc = f & 255;
        float4v v = {0.f, 0.f, 0.f, 0.f};
        int node = node0 + rr;
        if (node < N_NODES)
            v = *(const float4v*)(x + (size_t)node * 256 + cc);
        __hip_bfloat16 b0 = __float2bfloat16(v.x), b1 = __float2bfloat16(v.y);
        __hip_bfloat16 b2 = __float2bfloat16(v.z), b3 = __float2bfloat16(v.w);
        unsigned int lo = (unsigned int)*(unsigned short*)&b0 | ((unsigned int)*(unsigned short*)&b1 << 16);
        unsigned int hi = (unsigned int)*(unsigned short*)&b2 | ((unsigned int)*(unsigned short*)&b3 << 16);
        unsigned int* dst = (unsigned int*)&xs[rr][cc];
        dst[0] = lo; dst[1] = hi;
    }
    __syncthreads();

    // --- MFMA main loop: 8 k-steps x (4 row tiles x 3 col slots) ---
    float4v acc[4][3];
    #pragma unroll
    for (int rt = 0; rt < 4; ++rt)
        #pragma unroll
        for (int s = 0; s < 3; ++s)
            acc[rt][s] = (float4v){0.f, 0.f, 0.f, 0.f};

    const char* xbase = (const char*)&xs[0][0];
    #pragma unroll
    for (int ks = 0; ks < 8; ++ks) {
        short8 A[4];
        #pragma unroll
        for (int rt = 0; rt < 4; ++rt)
            A[rt] = *(const short8*)(xbase + (size_t)(rt * 16 + cl) * 528 + ks * 64 + kh * 16);
        #pragma unroll
        for (int rt = 0; rt < 4; ++rt)
            #pragma unroll
            for (int s = 0; s < 3; ++s)
                acc[rt][s] = __builtin_amdgcn_mfma_f32_16x16x32_bf16(A[rt], B[s][ks], acc[rt][s], 0, 0, 0);
    }

    // --- epilogue: bias + packed bf16 tables ---
    const int c0 = 16 * w + cl;
    const float bias_hp = biasAll[c0];
    const float bias_lp = biasAll[c0 + 64];
    const float bias_i  = biasAll[c0 + 128];

    #pragma unroll
    for (int rt = 0; rt < 4; ++rt) {
        #pragma unroll
        for (int r = 0; r < 4; ++r) {
            int node = node0 + rt * 16 + kh * 4 + r;
            if (node >= N_NODES) continue;
            float vhp = acc[rt][0][r] + bias_hp;
            float vlp = acc[rt][1][r] + bias_lp;
            float vi  = acc[rt][2][r] + bias_i;
            __hip_bfloat16 bh = __float2bfloat16(vhp);
            __hip_bfloat16 bl = __float2bfloat16(vlp);
            __hip_bfloat16 bb = __float2bfloat16(vi);
            hg[(size_t)node * 64 + c0] =
                (unsigned int)*(unsigned short*)&bh | ((unsigned int)*(unsigned short*)&bl << 16);
            hgi[(size_t)node * 64 + c0] = *(unsigned short*)&bb;
        }
    }
}

// ---------------------------------------------------------------------------
// Kernel 7: fused aggregation + gates + log_softmax. One wave per node, lane =
// feature dim. One coalesced 4B/lane (256B/wave) gather per neighbor.
// ---------------------------------------------------------------------------
__device__ __forceinline__ float wave_sum(float x) {
    #pragma unroll
    for (int off = 32; off > 0; off >>= 1) x += __shfl_xor(x, off);
    return x;
}
__device__ __forceinline__ float wave_max(float x) {
    #pragma unroll
    for (int off = 32; off > 0; off >>= 1) x = fmaxf(x, __shfl_xor(x, off));
    return x;
}

__global__ __launch_bounds__(256) void agg_kernel(
    const unsigned int* __restrict__ hg,
    const unsigned short* __restrict__ hgi,
    const int* __restrict__ offs,
    const unsigned int* __restrict__ csr,
    const float* __restrict__ isq,
    const float* __restrict__ dinv,
    const float* __restrict__ w_gh, const float* __restrict__ b_gh,
    const float* __restrict__ w_gl, const float* __restrict__ b_gl,
    const float* __restrict__ w_gi, const float* __restrict__ b_gi,
    float* __restrict__ out) {
    int v = blockIdx.x * 4 + (threadIdx.x >> 6);
    int lane = threadIdx.x & 63;
    if (v >= N_NODES) return;

    int start = offs[v], end = offs[v + 1];
    float isqv = isq[v];
    float acc_hp = 0.f, acc_lp = 0.f;

    for (int j0 = start; j0 < end; j0 += 64) {
        int m = end - j0; if (m > 64) m = 64;
        unsigned int uu = 0; float nn = 0.f;
        if (lane < m) {
            uu = csr[j0 + lane];
            nn = isq[uu] * isqv;            // isq: 400KB, L2-resident on each XCD
        }
        #pragma unroll 4
        for (int k = 0; k < m; ++k) {
            unsigned int u = __shfl(uu, k);
            float nrm = __shfl(nn, k);
            unsigned int g = hg[(size_t)u * 64 + lane];
            acc_hp = fmaf(nrm, __uint_as_float(g << 16), acc_hp);
            acc_lp = fmaf(nrm, __uint_as_float(g & 0xffff0000u), acc_lp);
        }
    }

    unsigned int gv = hg[(size_t)v * 64 + lane];
    float hhp = __uint_as_float(gv << 16);
    float hlp = __uint_as_float(gv & 0xffff0000u);
    float hi  = __uint_as_float((unsigned int)hgi[(size_t)v * 64 + lane] << 16);

    float dv = dinv[v];
    float Hhp = fmaxf(hhp - (acc_hp + dv * hhp), 0.f);
    float Hlp = fmaxf(acc_lp + dv * hlp, 0.f);
    float Hi  = fmaxf(hi, 0.f);

    float sh = wave_sum(Hhp * w_gh[lane]) + b_gh[0];
    float sl = wave_sum(Hlp * w_gl[lane]) + b_gl[0];
    float si = wave_sum(Hi  * w_gi[lane]) + b_gi[0];

    float o = sh * Hhp + sl * Hlp + si * Hi;
    float mx = wave_max(o);
    float se = wave_sum(expf(o - mx));
    out[(size_t)v * 64 + lane] = o - mx - logf(se);
}

// ---------------------------------------------------------------------------
static inline size_t align256(size_t v) { return (v + 255) & ~(size_t)255; }

extern "C" void kernel_launch(void* const* d_in, const int* in_sizes, int n_in,
                              void* d_out, int out_size, void* d_ws, size_t ws_size,
                              hipStream_t stream) {
    const float* x    = (const float*)d_in[0];
    const void*  ei   = d_in[1];
    const float* Whp  = (const float*)d_in[2];
    const float* bhp  = (const float*)d_in[3];
    const float* Wlp  = (const float*)d_in[4];
    const float* blp  = (const float*)d_in[5];
    const float* Wi   = (const float*)d_in[6];
    const float* bi   = (const float*)d_in[7];
    const float* w_gh = (const float*)d_in[8];
    const float* b_gh = (const float*)d_in[9];
    const float* w_gl = (const float*)d_in[10];
    const float* b_gl = (const float*)d_in[11];
    const float* w_gi = (const float*)d_in[12];
    const float* b_gi = (const float*)d_in[13];
    float* out = (float*)d_out;

    const int N = N_NODES, E = N_EDGES;

    // workspace layout (256B-aligned regions)
    char* base = (char*)d_ws;
    size_t off = 0;
    int* flag = (int*)(base + off);            off = align256(off + sizeof(int));
    int* hist2 = (int*)(base + off);           off = align256(off + 64 * 4);
    size_t zero_end_marker = off;              // memset covers [0, zero_end_marker + 8N*4)
    int* deg_priv = (int*)(base + off);        off = align256(off + (size_t)8 * N * 4);
    int* deg = (int*)(base + off);             off = align256(off + (size_t)N * 4);
    int* offs = (int*)(base + off);            off = align256(off + (size_t)(N + 1) * 4);
    int* cursor = (int*)(base + off);          off = align256(off + (size_t)N * 4);
    float* isq = (float*)(base + off);         off = align256(off + (size_t)N * 4);
    float* dinv = (float*)(base + off);        off = align256(off + (size_t)N * 4);
    int* bsum = (int*)(base + off);            off = align256(off + (size_t)NB_SCAN * 4);
    int* bukcur2 = (int*)(base + off);         off = align256(off + 64 * 4);
    uint2* bukbuf = (uint2*)(base + off);      off = align256(off + (size_t)E * 8);
    unsigned int* csr = (unsigned int*)(base + off); off = align256(off + (size_t)E * 4);
    float* biasAll = (float*)(base + off);     off = align256(off + 192 * 4);
    __hip_bfloat16* Wt = (__hip_bfloat16*)(base + off); off = align256(off + 192 * 256 * 2);
    unsigned int* hg = (unsigned int*)(base + off);   off = align256(off + (size_t)N * 64 * 4);
    unsigned short* hgi = (unsigned short*)(base + off); off = align256(off + (size_t)N * 64 * 2);

    // zero flag + hist2 + deg_priv
    hipMemsetAsync(base, 0, zero_end_marker + (size_t)8 * N * 4, stream);

    detect_dtype_kernel<<<1, 256, 0, stream>>>((const int*)ei, flag);
    degree_hist_kernel<<<EDGE_GRID, 256, 0, stream>>>(ei, flag, deg_priv, hist2);
    scan1_kernel<<<NB_SCAN, 256, 0, stream>>>(deg_priv, deg, bsum);
    scan2_kernel<<<1, 512, 0, stream>>>(bsum);
    scan3_kernel<<<NB_SCAN, 256, 0, stream>>>(deg, bsum, offs, cursor, isq, dinv);
    bukbase_kernel<<<1, 64, 0, stream>>>(offs, hist2, bukcur2);
    binfill_kernel<<<EDGE_GRID, 256, 0, stream>>>(ei, flag, bukcur2, bukbuf);
    scatter_kernel<<<2048, 256, 0, stream>>>(bukbuf, offs, cursor, csr);
    prep_w_kernel<<<192, 256, 0, stream>>>(Whp, bhp, Wlp, blp, Wi, bi, Wt, biasAll);
    gemm_kernel<<<(N + 63) / 64, 256, 0, stream>>>(x, Wt, biasAll, hg, hgi);
    agg_kernel<<<(N + 3) / 4, 256, 0, stream>>>(hg, hgi, offs, csr, isq, dinv,
                                                w_gh, b_gh, w_gl, b_gl, w_gi, b_gi, out);
}

// Round 6
// 538.855 us; speedup vs baseline: 4.5495x; 4.5495x over previous
//
#include <hip/hip_runtime.h>
#include <hip/hip_bf16.h>

#define N_NODES 100000
#define N_EDGES 3200000
#define IN_DIM  256
#define OUT_DIM 64
#define NB_SCAN ((N_NODES + 255) / 256)   // 391
#define NBUK 8
#define BUK_RANGE 12500                   // 8 * 12500 == 100000 exactly
#define EDGE_GRID 2048                    // 256 blocks per XCD class

typedef __attribute__((ext_vector_type(8))) short short8;
typedef __attribute__((ext_vector_type(4))) float float4v;

// ---------------------------------------------------------------------------
// Kernel 1: detect edge_index dtype (sampled). int64 (values < 2^31) -> every
// odd 32-bit word is 0. int32 -> odd words are node ids, nonzero w.h.p.
// flag=1 -> int32.
// ---------------------------------------------------------------------------
__global__ void detect_dtype_kernel(const int* __restrict__ ei32, int* __restrict__ flag) {
    int i = threadIdx.x;
    int found = 0;
    for (int w = 2 * i + 1; w < 8192; w += 512)
        found |= (ei32[w] != 0);
    if (found) atomicOr(flag, 1);
}

__device__ __forceinline__ int load_dst(const void* ei, int e, bool is64) {
    return is64 ? (int)((const long long*)ei)[N_EDGES + e]
                : ((const int*)ei)[N_EDGES + e];
}
__device__ __forceinline__ int load_src(const void* ei, int e, bool is64) {
    return is64 ? (int)((const long long*)ei)[e]
                : ((const int*)ei)[e];
}

// ---------------------------------------------------------------------------
// Kernel 2: degree count, XCD-bucketed. Class c = blockIdx%8 (consecutive
// blocks round-robin XCDs) handles only dst in [c*12500,(c+1)*12500): its
// 50KB deg window + atomics stay in XCD-c's L2. Each class streams the whole
// (L3-served) dst array.
// ---------------------------------------------------------------------------
__global__ __launch_bounds__(256) void degree_kernel(
    const void* __restrict__ ei, const int* __restrict__ flag,
    int* __restrict__ deg) {
    bool is64 = (*flag == 0);
    int c = blockIdx.x & 7;
    int i = (blockIdx.x >> 3) * 256 + threadIdx.x;
    int stride = 256 * (EDGE_GRID / 8);
    for (int e = i; e < N_EDGES; e += stride) {
        int d = load_dst(ei, e, is64);
        if (d / BUK_RANGE == c)
            atomicAdd(&deg[d], 1);
    }
}

// ---------------------------------------------------------------------------
// Kernels 3a/3b/3c: hierarchical exclusive scan -> offs/cursor/isq/dinv/rsd
// ---------------------------------------------------------------------------
__global__ __launch_bounds__(256) void scan1_kernel(const int* __restrict__ deg,
                                                    int* __restrict__ bsum) {
    __shared__ int red[256];
    int tid = threadIdx.x;
    int i = blockIdx.x * 256 + tid;
    int v = (i < N_NODES) ? deg[i] : 0;
    red[tid] = v;
    __syncthreads();
    #pragma unroll
    for (int off = 128; off > 0; off >>= 1) {
        if (tid < off) red[tid] += red[tid + off];
        __syncthreads();
    }
    if (tid == 0) bsum[blockIdx.x] = red[0];
}

__global__ __launch_bounds__(512) void scan2_kernel(int* __restrict__ bsum) {
    __shared__ int sh[512];
    int tid = threadIdx.x;
    int v = (tid < NB_SCAN) ? bsum[tid] : 0;
    sh[tid] = v;
    __syncthreads();
    int val = v;
    #pragma unroll
    for (int off = 1; off < 512; off <<= 1) {
        int t = (tid >= off) ? sh[tid - off] : 0;
        __syncthreads();
        val += t;
        sh[tid] = val;
        __syncthreads();
    }
    if (tid < NB_SCAN) bsum[tid] = val - v;   // exclusive block prefix
}

__global__ __launch_bounds__(256) void scan3_kernel(const int* __restrict__ deg,
                                                    const int* __restrict__ bsum,
                                                    int* __restrict__ offs,
                                                    int* __restrict__ cursor,
                                                    float* __restrict__ isq,
                                                    float* __restrict__ dinv,
                                                    float* __restrict__ rsd) {
    __shared__ int sh[256];
    int tid = threadIdx.x;
    int i = blockIdx.x * 256 + tid;
    int d = (i < N_NODES) ? deg[i] : 0;
    sh[tid] = d;
    __syncthreads();
    int val = d;
    #pragma unroll
    for (int off = 1; off < 256; off <<= 1) {
        int t = (tid >= off) ? sh[tid - off] : 0;
        __syncthreads();
        val += t;
        sh[tid] = val;
        __syncthreads();
    }
    int ex = bsum[blockIdx.x] + val - d;      // exclusive prefix for node i
    if (i < N_NODES) {
        offs[i] = ex;
        cursor[i] = ex;
        float dr = (float)(d + 1);
        isq[i] = rsqrtf(dr);
        dinv[i] = 1.0f / dr;
        rsd[i] = sqrtf(dr);
    }
    if (i == 0) offs[N_NODES] = N_EDGES;      // total degree == E by construction
}

// ---------------------------------------------------------------------------
// Kernel 4: CSR fill, XCD-bucketed like degree: class c's cursor window (50KB)
// and csr window (~1.6MB) stay in XCD-c's L2 -> full-line single write-back.
// ---------------------------------------------------------------------------
__global__ __launch_bounds__(256) void fill_kernel(
    const void* __restrict__ ei, const int* __restrict__ flag,
    int* __restrict__ cursor, unsigned int* __restrict__ csr) {
    bool is64 = (*flag == 0);
    int c = blockIdx.x & 7;
    int i = (blockIdx.x >> 3) * 256 + threadIdx.x;
    int stride = 256 * (EDGE_GRID / 8);
    for (int e = i; e < N_EDGES; e += stride) {
        int d = load_dst(ei, e, is64);
        if (d / BUK_RANGE == c) {
            int s = load_src(ei, e, is64);
            int pos = atomicAdd(&cursor[d], 1);
            csr[pos] = (unsigned int)s;
        }
    }
}

// ---------------------------------------------------------------------------
// Kernel 5: prep weights: Wt[c][k] = bf16(W[k][c]), bias vector biasAll[192].
// ---------------------------------------------------------------------------
__global__ void prep_w_kernel(const float* __restrict__ Whp, const float* __restrict__ bhp,
                              const float* __restrict__ Wlp, const float* __restrict__ blp,
                              const float* __restrict__ Wi,  const float* __restrict__ bi,
                              __hip_bfloat16* __restrict__ Wt, float* __restrict__ biasAll) {
    int c = blockIdx.x;      // 0..191
    int k = threadIdx.x;     // 0..255
    const float* W = (c < 64) ? Whp : (c < 128) ? Wlp : Wi;
    int cl = c & 63;
    Wt[c * 256 + k] = __float2bfloat16(W[k * 64 + cl]);
    if (k == 0) {
        const float* b = (c < 64) ? bhp : (c < 128) ? blp : bi;
        biasAll[c] = b[cl];
    }
}

// ---------------------------------------------------------------------------
// Kernel 6: bf16 MFMA GEMM. Block = 256 threads (4 waves), 64 nodes.
// hg rows are PRE-SCALED by isq[node] (folds the per-edge norm into the
// gather table); hgi (i branch) stays unscaled.
// ---------------------------------------------------------------------------
__global__ __launch_bounds__(256) void gemm_kernel(
    const float* __restrict__ x,
    const __hip_bfloat16* __restrict__ Wt,
    const float* __restrict__ biasAll,
    const float* __restrict__ isq,
    unsigned int* __restrict__ hg, unsigned short* __restrict__ hgi) {

    __shared__ __align__(16) __hip_bfloat16 xs[64][264];

    const int tid = threadIdx.x;
    const int node0 = blockIdx.x * 64;
    const int w = tid >> 6;
    const int lane = tid & 63;
    const int cl = lane & 15;
    const int kh = lane >> 4;

    // --- B fragments: Wt[col][ks*32 + kh*8 .. +8], col = 16w + 64s + cl ---
    short8 B[3][8];
    #pragma unroll
    for (int s = 0; s < 3; ++s) {
        const __hip_bfloat16* wp = Wt + (16 * w + 64 * s + cl) * 256 + kh * 8;
        #pragma unroll
        for (int ks = 0; ks < 8; ++ks)
            B[s][ks] = *(const short8*)(wp + ks * 32);
    }

    // --- stage x tile (64 x 256 f32 -> bf16 LDS), coalesced 16B/lane ---
    #pragma unroll
    for (int j = 0; j < 16; ++j) {
        int f = j * 1024 + tid * 4;          // flat float index in tile
        int rr = f >> 8, cc = f & 255;
        float4v v = {0.f, 0.f, 0.f, 0.f};
        int node = node0 + rr;
        if (node < N_NODES)
            v = *(const float4v*)(x + (size_t)node * 256 + cc);
        __hip_bfloat16 b0 = __float2bfloat16(v.x), b1 = __float2bfloat16(v.y);
        __hip_bfloat16 b2 = __float2bfloat16(v.z), b3 = __float2bfloat16(v.w);
        unsigned int lo = (unsigned int)*(unsigned short*)&b0 | ((unsigned int)*(unsigned short*)&b1 << 16);
        unsigned int hi = (unsigned int)*(unsigned short*)&b2 | ((unsigned int)*(unsigned short*)&b3 << 16);
        unsigned int* dst = (unsigned int*)&xs[rr][cc];
        dst[0] = lo; dst[1] = hi;
    }
    __syncthreads();

    // --- MFMA main loop: 8 k-steps x (4 row tiles x 3 col slots) ---
    float4v acc[4][3];
    #pragma unroll
    for (int rt = 0; rt < 4; ++rt)
        #pragma unroll
        for (int s = 0; s < 3; ++s)
            acc[rt][s] = (float4v){0.f, 0.f, 0.f, 0.f};

    const char* xbase = (const char*)&xs[0][0];
    #pragma unroll
    for (int ks = 0; ks < 8; ++ks) {
        short8 A[4];
        #pragma unroll
        for (int rt = 0; rt < 4; ++rt)
            A[rt] = *(const short8*)(xbase + (size_t)(rt * 16 + cl) * 528 + ks * 64 + kh * 16);
        #pragma unroll
        for (int rt = 0; rt < 4; ++rt)
            #pragma unroll
            for (int s = 0; s < 3; ++s)
                acc[rt][s] = __builtin_amdgcn_mfma_f32_16x16x32_bf16(A[rt], B[s][ks], acc[rt][s], 0, 0, 0);
    }

    // --- epilogue: bias, isq-scale hp/lp, pack bf16 tables ---
    const int c0 = 16 * w + cl;
    const float bias_hp = biasAll[c0];
    const float bias_lp = biasAll[c0 + 64];
    const float bias_i  = biasAll[c0 + 128];

    #pragma unroll
    for (int rt = 0; rt < 4; ++rt) {
        #pragma unroll
        for (int r = 0; r < 4; ++r) {
            int node = node0 + rt * 16 + kh * 4 + r;
            if (node >= N_NODES) continue;
            float sq = isq[node];
            float vhp = (acc[rt][0][r] + bias_hp) * sq;
            float vlp = (acc[rt][1][r] + bias_lp) * sq;
            float vi  = acc[rt][2][r] + bias_i;
            __hip_bfloat16 bh = __float2bfloat16(vhp);
            __hip_bfloat16 bl = __float2bfloat16(vlp);
            __hip_bfloat16 bb = __float2bfloat16(vi);
            hg[(size_t)node * 64 + c0] =
                (unsigned int)*(unsigned short*)&bh | ((unsigned int)*(unsigned short*)&bl << 16);
            hgi[(size_t)node * 64 + c0] = *(unsigned short*)&bb;
        }
    }
}

// ---------------------------------------------------------------------------
// Kernel 7: fused aggregation + gates + log_softmax. One wave per node, lane =
// feature dim. Inner loop: one 4B/lane gather + 2 unpacks + 2 adds (norm is
// pre-folded into hg; isq[v] applied once after the loop).
// ---------------------------------------------------------------------------
__device__ __forceinline__ float wave_sum(float x) {
    #pragma unroll
    for (int off = 32; off > 0; off >>= 1) x += __shfl_xor(x, off);
    return x;
}
__device__ __forceinline__ float wave_max(float x) {
    #pragma unroll
    for (int off = 32; off > 0; off >>= 1) x = fmaxf(x, __shfl_xor(x, off));
    return x;
}

__global__ __launch_bounds__(256) void agg_kernel(
    const unsigned int* __restrict__ hg,
    const unsigned short* __restrict__ hgi,
    const int* __restrict__ offs,
    const unsigned int* __restrict__ csr,
    const float* __restrict__ isq,
    const float* __restrict__ dinv,
    const float* __restrict__ rsd,
    const float* __restrict__ w_gh, const float* __restrict__ b_gh,
    const float* __restrict__ w_gl, const float* __restrict__ b_gl,
    const float* __restrict__ w_gi, const float* __restrict__ b_gi,
    float* __restrict__ out) {
    int v = blockIdx.x * 4 + (threadIdx.x >> 6);
    int lane = threadIdx.x & 63;
    if (v >= N_NODES) return;

    int start = offs[v], end = offs[v + 1];
    float acc_hp = 0.f, acc_lp = 0.f;

    for (int j0 = start; j0 < end; j0 += 64) {
        int m = end - j0; if (m > 64) m = 64;
        unsigned int uu = 0;
        if (lane < m) uu = csr[j0 + lane];
        #pragma unroll 4
        for (int k = 0; k < m; ++k) {
            unsigned int u = __shfl(uu, k);
            unsigned int g = hg[(size_t)u * 64 + lane];
            acc_hp += __uint_as_float(g << 16);
            acc_lp += __uint_as_float(g & 0xffff0000u);
        }
    }

    float isqv = isq[v];
    float agg_hp = acc_hp * isqv;
    float agg_lp = acc_lp * isqv;

    unsigned int gv = hg[(size_t)v * 64 + lane];
    float rv = rsd[v];
    float hhp = __uint_as_float(gv << 16) * rv;          // un-scale self row
    float hlp = __uint_as_float(gv & 0xffff0000u) * rv;
    float hi  = __uint_as_float((unsigned int)hgi[(size_t)v * 64 + lane] << 16);

    float dv = dinv[v];
    float Hhp = fmaxf(hhp - (agg_hp + dv * hhp), 0.f);
    float Hlp = fmaxf(agg_lp + dv * hlp, 0.f);
    float Hi  = fmaxf(hi, 0.f);

    float sh = wave_sum(Hhp * w_gh[lane]) + b_gh[0];
    float sl = wave_sum(Hlp * w_gl[lane]) + b_gl[0];
    float si = wave_sum(Hi  * w_gi[lane]) + b_gi[0];

    float o = sh * Hhp + sl * Hlp + si * Hi;
    float mx = wave_max(o);
    float se = wave_sum(expf(o - mx));
    out[(size_t)v * 64 + lane] = o - mx - logf(se);
}

// ---------------------------------------------------------------------------
static inline size_t align256(size_t v) { return (v + 255) & ~(size_t)255; }

extern "C" void kernel_launch(void* const* d_in, const int* in_sizes, int n_in,
                              void* d_out, int out_size, void* d_ws, size_t ws_size,
                              hipStream_t stream) {
    const float* x    = (const float*)d_in[0];
    const void*  ei   = d_in[1];
    const float* Whp  = (const float*)d_in[2];
    const float* bhp  = (const float*)d_in[3];
    const float* Wlp  = (const float*)d_in[4];
    const float* blp  = (const float*)d_in[5];
    const float* Wi   = (const float*)d_in[6];
    const float* bi   = (const float*)d_in[7];
    const float* w_gh = (const float*)d_in[8];
    const float* b_gh = (const float*)d_in[9];
    const float* w_gl = (const float*)d_in[10];
    const float* b_gl = (const float*)d_in[11];
    const float* w_gi = (const float*)d_in[12];
    const float* b_gi = (const float*)d_in[13];
    float* out = (float*)d_out;

    const int N = N_NODES, E = N_EDGES;

    // workspace layout (256B-aligned regions)
    char* base = (char*)d_ws;
    size_t off = 0;
    int* flag = (int*)(base + off);            off = align256(off + sizeof(int));
    size_t deg_off = off;
    int* deg = (int*)(base + off);             off = align256(off + (size_t)N * 4);
    size_t zero_end = off;                     // memset covers [0, zero_end)
    int* offs = (int*)(base + off);            off = align256(off + (size_t)(N + 1) * 4);
    int* cursor = (int*)(base + off);          off = align256(off + (size_t)N * 4);
    float* isq = (float*)(base + off);         off = align256(off + (size_t)N * 4);
    float* dinv = (float*)(base + off);        off = align256(off + (size_t)N * 4);
    float* rsd = (float*)(base + off);         off = align256(off + (size_t)N * 4);
    int* bsum = (int*)(base + off);            off = align256(off + (size_t)NB_SCAN * 4);
    unsigned int* csr = (unsigned int*)(base + off); off = align256(off + (size_t)E * 4);
    float* biasAll = (float*)(base + off);     off = align256(off + 192 * 4);
    __hip_bfloat16* Wt = (__hip_bfloat16*)(base + off); off = align256(off + 192 * 256 * 2);
    unsigned int* hg = (unsigned int*)(base + off);   off = align256(off + (size_t)N * 64 * 4);
    unsigned short* hgi = (unsigned short*)(base + off); off = align256(off + (size_t)N * 64 * 2);
    (void)deg_off;

    // zero flag + deg
    hipMemsetAsync(base, 0, zero_end, stream);

    detect_dtype_kernel<<<1, 256, 0, stream>>>((const int*)ei, flag);
    degree_kernel<<<EDGE_GRID, 256, 0, stream>>>(ei, flag, deg);
    scan1_kernel<<<NB_SCAN, 256, 0, stream>>>(deg, bsum);
    scan2_kernel<<<1, 512, 0, stream>>>(bsum);
    scan3_kernel<<<NB_SCAN, 256, 0, stream>>>(deg, bsum, offs, cursor, isq, dinv, rsd);
    fill_kernel<<<EDGE_GRID, 256, 0, stream>>>(ei, flag, cursor, csr);
    prep_w_kernel<<<192, 256, 0, stream>>>(Whp, bhp, Wlp, blp, Wi, bi, Wt, biasAll);
    gemm_kernel<<<(N + 63) / 64, 256, 0, stream>>>(x, Wt, biasAll, isq, hg, hgi);
    agg_kernel<<<(N + 3) / 4, 256, 0, stream>>>(hg, hgi, offs, csr, isq, dinv, rsd,
                                                w_gh, b_gh, w_gl, b_gl, w_gi, b_gi, out);
}

// Round 7
// 527.147 us; speedup vs baseline: 4.6505x; 1.0222x over previous
//
#include <hip/hip_runtime.h>
#include <hip/hip_bf16.h>

#define N_NODES 100000
#define N_EDGES 3200000
#define IN_DIM  256
#define OUT_DIM 64
#define NB_SCAN ((N_NODES + 255) / 256)   // 391
#define NBUK 8
#define BUK_RANGE 12500                   // 8 * 12500 == 100000 exactly
#define EDGE_GRID 2048                    // 256 blocks per XCD class

typedef __attribute__((ext_vector_type(8))) short short8;
typedef __attribute__((ext_vector_type(4))) float float4v;
typedef __attribute__((ext_vector_type(2))) float floatx2;

// ---------------------------------------------------------------------------
// fp8 e4m3 pack/unpack (HW cvt on gfx950, software fallback for safety)
// ---------------------------------------------------------------------------
__device__ __forceinline__ unsigned int enc_fp8_sw(float v) {
    unsigned int u = __float_as_uint(v);
    unsigned int s = (u >> 24) & 0x80u;
    unsigned int mag = u & 0x7fffffffu;
    unsigned int q;
    if (mag >= 0x43e00000u) q = 0x7e;                 // >=448 or NaN -> clamp to max
    else if (mag < 0x3c800000u) {                     // < 2^-6 -> subnormal
        float av = __uint_as_float(mag);
        q = (unsigned int)(av * 512.0f + 0.5f);       // <=8; 8 == 2^-6 normal, ok
    } else {
        unsigned int mr = mag + 0x00080000u;          // round at bit 19
        unsigned int e = (mr >> 23) - 127 + 7;
        unsigned int m = (mr >> 20) & 7;
        q = (e << 3) | m;
        if (q > 0x7e) q = 0x7e;
    }
    return s | q;
}
__device__ __forceinline__ float dec_fp8_sw(unsigned int b) {
    unsigned int s = (b & 0x80u) << 24;
    unsigned int e = (b >> 3) & 15u, m = b & 7u;
    float f = (e == 0) ? (float)m * 0.001953125f
                       : __uint_as_float(((e + 120u) << 23) | (m << 20));
    return __uint_as_float(__float_as_uint(f) | s);
}

__device__ __forceinline__ unsigned short pack_fp8x2(float lo, float hi) {
#if __has_builtin(__builtin_amdgcn_cvt_pk_fp8_f32)
    int p = __builtin_amdgcn_cvt_pk_fp8_f32(lo, hi, 0, false);
    return (unsigned short)((unsigned int)p & 0xffffu);
#else
    return (unsigned short)(enc_fp8_sw(lo) | (enc_fp8_sw(hi) << 8));
#endif
}
__device__ __forceinline__ void unpack_fp8x2(unsigned short g, float& lo, float& hi) {
#if __has_builtin(__builtin_amdgcn_cvt_pk_f32_fp8)
    floatx2 v = __builtin_amdgcn_cvt_pk_f32_fp8((int)(unsigned int)g, false);
    lo = v[0]; hi = v[1];
#else
    lo = dec_fp8_sw(g & 0xffu); hi = dec_fp8_sw((g >> 8) & 0xffu);
#endif
}

// ---------------------------------------------------------------------------
// Kernel 1: detect edge_index dtype (sampled). int64 (values < 2^31) -> every
// odd 32-bit word is 0. int32 -> odd words are node ids, nonzero w.h.p.
// flag=1 -> int32.
// ---------------------------------------------------------------------------
__global__ void detect_dtype_kernel(const int* __restrict__ ei32, int* __restrict__ flag) {
    int i = threadIdx.x;
    int found = 0;
    for (int w = 2 * i + 1; w < 8192; w += 512)
        found |= (ei32[w] != 0);
    if (found) atomicOr(flag, 1);
}

__device__ __forceinline__ int load_dst(const void* ei, int e, bool is64) {
    return is64 ? (int)((const long long*)ei)[N_EDGES + e]
                : ((const int*)ei)[N_EDGES + e];
}
__device__ __forceinline__ int load_src(const void* ei, int e, bool is64) {
    return is64 ? (int)((const long long*)ei)[e]
                : ((const int*)ei)[e];
}

// ---------------------------------------------------------------------------
// Kernel 2: degree count, XCD-bucketed (class c=blockIdx%8 handles only dst in
// its 12.5k-node window; atomics stay in one XCD's L2).
// ---------------------------------------------------------------------------
__global__ __launch_bounds__(256) void degree_kernel(
    const void* __restrict__ ei, const int* __restrict__ flag,
    int* __restrict__ deg) {
    bool is64 = (*flag == 0);
    int c = blockIdx.x & 7;
    int i = (blockIdx.x >> 3) * 256 + threadIdx.x;
    int stride = 256 * (EDGE_GRID / 8);
    for (int e = i; e < N_EDGES; e += stride) {
        int d = load_dst(ei, e, is64);
        if (d / BUK_RANGE == c)
            atomicAdd(&deg[d], 1);
    }
}

// ---------------------------------------------------------------------------
// Kernels 3a/3b/3c: hierarchical exclusive scan -> offs/cursor/isq/dinv
// ---------------------------------------------------------------------------
__global__ __launch_bounds__(256) void scan1_kernel(const int* __restrict__ deg,
                                                    int* __restrict__ bsum) {
    __shared__ int red[256];
    int tid = threadIdx.x;
    int i = blockIdx.x * 256 + tid;
    int v = (i < N_NODES) ? deg[i] : 0;
    red[tid] = v;
    __syncthreads();
    #pragma unroll
    for (int off = 128; off > 0; off >>= 1) {
        if (tid < off) red[tid] += red[tid + off];
        __syncthreads();
    }
    if (tid == 0) bsum[blockIdx.x] = red[0];
}

__global__ __launch_bounds__(512) void scan2_kernel(int* __restrict__ bsum) {
    __shared__ int sh[512];
    int tid = threadIdx.x;
    int v = (tid < NB_SCAN) ? bsum[tid] : 0;
    sh[tid] = v;
    __syncthreads();
    int val = v;
    #pragma unroll
    for (int off = 1; off < 512; off <<= 1) {
        int t = (tid >= off) ? sh[tid - off] : 0;
        __syncthreads();
        val += t;
        sh[tid] = val;
        __syncthreads();
    }
    if (tid < NB_SCAN) bsum[tid] = val - v;   // exclusive block prefix
}

__global__ __launch_bounds__(256) void scan3_kernel(const int* __restrict__ deg,
                                                    const int* __restrict__ bsum,
                                                    int* __restrict__ offs,
                                                    int* __restrict__ cursor,
                                                    float* __restrict__ isq,
                                                    float* __restrict__ dinv) {
    __shared__ int sh[256];
    int tid = threadIdx.x;
    int i = blockIdx.x * 256 + tid;
    int d = (i < N_NODES) ? deg[i] : 0;
    sh[tid] = d;
    __syncthreads();
    int val = d;
    #pragma unroll
    for (int off = 1; off < 256; off <<= 1) {
        int t = (tid >= off) ? sh[tid - off] : 0;
        __syncthreads();
        val += t;
        sh[tid] = val;
        __syncthreads();
    }
    int ex = bsum[blockIdx.x] + val - d;      // exclusive prefix for node i
    if (i < N_NODES) {
        offs[i] = ex;
        cursor[i] = ex;
        float dr = (float)(d + 1);
        isq[i] = rsqrtf(dr);
        dinv[i] = 1.0f / dr;
    }
    if (i == 0) offs[N_NODES] = N_EDGES;      // total degree == E by construction
}

// ---------------------------------------------------------------------------
// Kernel 4: CSR fill, XCD-bucketed like degree.
// ---------------------------------------------------------------------------
__global__ __launch_bounds__(256) void fill_kernel(
    const void* __restrict__ ei, const int* __restrict__ flag,
    int* __restrict__ cursor, unsigned int* __restrict__ csr) {
    bool is64 = (*flag == 0);
    int c = blockIdx.x & 7;
    int i = (blockIdx.x >> 3) * 256 + threadIdx.x;
    int stride = 256 * (EDGE_GRID / 8);
    for (int e = i; e < N_EDGES; e += stride) {
        int d = load_dst(ei, e, is64);
        if (d / BUK_RANGE == c) {
            int s = load_src(ei, e, is64);
            int pos = atomicAdd(&cursor[d], 1);
            csr[pos] = (unsigned int)s;
        }
    }
}

// ---------------------------------------------------------------------------
// Kernel 5: prep weights: Wt[c][k] = bf16(W[k][c]), bias vector biasAll[192].
// ---------------------------------------------------------------------------
__global__ void prep_w_kernel(const float* __restrict__ Whp, const float* __restrict__ bhp,
                              const float* __restrict__ Wlp, const float* __restrict__ blp,
                              const float* __restrict__ Wi,  const float* __restrict__ bi,
                              __hip_bfloat16* __restrict__ Wt, float* __restrict__ biasAll) {
    int c = blockIdx.x;      // 0..191
    int k = threadIdx.x;     // 0..255
    const float* W = (c < 64) ? Whp : (c < 128) ? Wlp : Wi;
    int cl = c & 63;
    Wt[c * 256 + k] = __float2bfloat16(W[k * 64 + cl]);
    if (k == 0) {
        const float* b = (c < 64) ? bhp : (c < 128) ? blp : bi;
        biasAll[c] = b[cl];
    }
}

// ---------------------------------------------------------------------------
// Kernel 6: bf16 MFMA GEMM. Block = 256 threads (4 waves), 64 nodes.
// Writes: hq = fp8x2{hp,lp}·isq (gather table), hg = bf16x2{hp,lp} unscaled
// (self rows), hgi = bf16 i-branch.
// ---------------------------------------------------------------------------
__global__ __launch_bounds__(256) void gemm_kernel(
    const float* __restrict__ x,
    const __hip_bfloat16* __restrict__ Wt,
    const float* __restrict__ biasAll,
    const float* __restrict__ isq,
    unsigned short* __restrict__ hq,
    unsigned int* __restrict__ hg, unsigned short* __restrict__ hgi) {

    __shared__ __align__(16) __hip_bfloat16 xs[64][264];

    const int tid = threadIdx.x;
    const int node0 = blockIdx.x * 64;
    const int w = tid >> 6;
    const int lane = tid & 63;
    const int cl = lane & 15;
    const int kh = lane >> 4;

    // --- B fragments: Wt[col][ks*32 + kh*8 .. +8], col = 16w + 64s + cl ---
    short8 B[3][8];
    #pragma unroll
    for (int s = 0; s < 3; ++s) {
        const __hip_bfloat16* wp = Wt + (16 * w + 64 * s + cl) * 256 + kh * 8;
        #pragma unroll
        for (int ks = 0; ks < 8; ++ks)
            B[s][ks] = *(const short8*)(wp + ks * 32);
    }

    // --- stage x tile (64 x 256 f32 -> bf16 LDS), coalesced 16B/lane ---
    #pragma unroll
    for (int j = 0; j < 16; ++j) {
        int f = j * 1024 + tid * 4;          // flat float index in tile
        int rr = f >> 8, cc = f & 255;
        float4v v = {0.f, 0.f, 0.f, 0.f};
        int node = node0 + rr;
        if (node < N_NODES)
            v = *(const float4v*)(x + (size_t)node * 256 + cc);
        __hip_bfloat16 b0 = __float2bfloat16(v.x), b1 = __float2bfloat16(v.y);
        __hip_bfloat16 b2 = __float2bfloat16(v.z), b3 = __float2bfloat16(v.w);
        unsigned int lo = (unsigned int)*(unsigned short*)&b0 | ((unsigned int)*(unsigned short*)&b1 << 16);
        unsigned int hi = (unsigned int)*(unsigned short*)&b2 | ((unsigned int)*(unsigned short*)&b3 << 16);
        unsigned int* dst = (unsigned int*)&xs[rr][cc];
        dst[0] = lo; dst[1] = hi;
    }
    __syncthreads();

    // --- MFMA main loop: 8 k-steps x (4 row tiles x 3 col slots) ---
    float4v acc[4][3];
    #pragma unroll
    for (int rt = 0; rt < 4; ++rt)
        #pragma unroll
        for (int s = 0; s < 3; ++s)
            acc[rt][s] = (float4v){0.f, 0.f, 0.f, 0.f};

    const char* xbase = (const char*)&xs[0][0];
    #pragma unroll
    for (int ks = 0; ks < 8; ++ks) {
        short8 A[4];
        #pragma unroll
        for (int rt = 0; rt < 4; ++rt)
            A[rt] = *(const short8*)(xbase + (size_t)(rt * 16 + cl) * 528 + ks * 64 + kh * 16);
        #pragma unroll
        for (int rt = 0; rt < 4; ++rt)
            #pragma unroll
            for (int s = 0; s < 3; ++s)
                acc[rt][s] = __builtin_amdgcn_mfma_f32_16x16x32_bf16(A[rt], B[s][ks], acc[rt][s], 0, 0, 0);
    }

    // --- epilogue: bias; fp8 gather table (isq-scaled) + bf16 self tables ---
    const int c0 = 16 * w + cl;
    const float bias_hp = biasAll[c0];
    const float bias_lp = biasAll[c0 + 64];
    const float bias_i  = biasAll[c0 + 128];

    #pragma unroll
    for (int rt = 0; rt < 4; ++rt) {
        #pragma unroll
        for (int r = 0; r < 4; ++r) {
            int node = node0 + rt * 16 + kh * 4 + r;
            if (node >= N_NODES) continue;
            float sq = isq[node];
            float vhp = acc[rt][0][r] + bias_hp;
            float vlp = acc[rt][1][r] + bias_lp;
            float vi  = acc[rt][2][r] + bias_i;
            hq[(size_t)node * 64 + c0] = pack_fp8x2(vhp * sq, vlp * sq);
            __hip_bfloat16 bh = __float2bfloat16(vhp);
            __hip_bfloat16 bl = __float2bfloat16(vlp);
            __hip_bfloat16 bb = __float2bfloat16(vi);
            hg[(size_t)node * 64 + c0] =
                (unsigned int)*(unsigned short*)&bh | ((unsigned int)*(unsigned short*)&bl << 16);
            hgi[(size_t)node * 64 + c0] = *(unsigned short*)&bb;
        }
    }
}

// ---------------------------------------------------------------------------
// Kernel 7: fused aggregation + gates + log_softmax. One wave per node, lane =
// feature dim. Inner loop: one 2B/lane fp8x2 gather (128B/wave) + 1 cvt + 2
// adds per neighbor. Self terms from bf16 tables.
// ---------------------------------------------------------------------------
__device__ __forceinline__ float wave_sum(float x) {
    #pragma unroll
    for (int off = 32; off > 0; off >>= 1) x += __shfl_xor(x, off);
    return x;
}
__device__ __forceinline__ float wave_max(float x) {
    #pragma unroll
    for (int off = 32; off > 0; off >>= 1) x = fmaxf(x, __shfl_xor(x, off));
    return x;
}

__global__ __launch_bounds__(256) void agg_kernel(
    const unsigned short* __restrict__ hq,
    const unsigned int* __restrict__ hg,
    const unsigned short* __restrict__ hgi,
    const int* __restrict__ offs,
    const unsigned int* __restrict__ csr,
    const float* __restrict__ isq,
    const float* __restrict__ dinv,
    const float* __restrict__ w_gh, const float* __restrict__ b_gh,
    const float* __restrict__ w_gl, const float* __restrict__ b_gl,
    const float* __restrict__ w_gi, const float* __restrict__ b_gi,
    float* __restrict__ out) {
    int v = blockIdx.x * 4 + (threadIdx.x >> 6);
    int lane = threadIdx.x & 63;
    if (v >= N_NODES) return;

    int start = offs[v], end = offs[v + 1];
    float acc_hp = 0.f, acc_lp = 0.f;

    for (int j0 = start; j0 < end; j0 += 64) {
        int m = end - j0; if (m > 64) m = 64;
        unsigned int uu = 0;
        if (lane < m) uu = csr[j0 + lane];
        #pragma unroll 4
        for (int k = 0; k < m; ++k) {
            unsigned int u = __shfl(uu, k);
            unsigned short g = hq[(size_t)u * 64 + lane];
            float lo, hi;
            unpack_fp8x2(g, lo, hi);
            acc_hp += lo;
            acc_lp += hi;
        }
    }

    float isqv = isq[v];
    float agg_hp = acc_hp * isqv;
    float agg_lp = acc_lp * isqv;

    unsigned int gv = hg[(size_t)v * 64 + lane];
    float hhp = __uint_as_float(gv << 16);
    float hlp = __uint_as_float(gv & 0xffff0000u);
    float hi  = __uint_as_float((unsigned int)hgi[(size_t)v * 64 + lane] << 16);

    float dv = dinv[v];
    float Hhp = fmaxf(hhp - (agg_hp + dv * hhp), 0.f);
    float Hlp = fmaxf(agg_lp + dv * hlp, 0.f);
    float Hi  = fmaxf(hi, 0.f);

    float sh = wave_sum(Hhp * w_gh[lane]) + b_gh[0];
    float sl = wave_sum(Hlp * w_gl[lane]) + b_gl[0];
    float si = wave_sum(Hi  * w_gi[lane]) + b_gi[0];

    float o = sh * Hhp + sl * Hlp + si * Hi;
    float mx = wave_max(o);
    float se = wave_sum(expf(o - mx));
    out[(size_t)v * 64 + lane] = o - mx - logf(se);
}

// ---------------------------------------------------------------------------
static inline size_t align256(size_t v) { return (v + 255) & ~(size_t)255; }

extern "C" void kernel_launch(void* const* d_in, const int* in_sizes, int n_in,
                              void* d_out, int out_size, void* d_ws, size_t ws_size,
                              hipStream_t stream) {
    const float* x    = (const float*)d_in[0];
    const void*  ei   = d_in[1];
    const float* Whp  = (const float*)d_in[2];
    const float* bhp  = (const float*)d_in[3];
    const float* Wlp  = (const float*)d_in[4];
    const float* blp  = (const float*)d_in[5];
    const float* Wi   = (const float*)d_in[6];
    const float* bi   = (const float*)d_in[7];
    const float* w_gh = (const float*)d_in[8];
    const float* b_gh = (const float*)d_in[9];
    const float* w_gl = (const float*)d_in[10];
    const float* b_gl = (const float*)d_in[11];
    const float* w_gi = (const float*)d_in[12];
    const float* b_gi = (const float*)d_in[13];
    float* out = (float*)d_out;

    const int N = N_NODES, E = N_EDGES;

    // workspace layout (256B-aligned regions)
    char* base = (char*)d_ws;
    size_t off = 0;
    int* flag = (int*)(base + off);            off = align256(off + sizeof(int));
    int* deg = (int*)(base + off);             off = align256(off + (size_t)N * 4);
    size_t zero_end = off;                     // memset covers [0, zero_end)
    int* offs = (int*)(base + off);            off = align256(off + (size_t)(N + 1) * 4);
    int* cursor = (int*)(base + off);          off = align256(off + (size_t)N * 4);
    float* isq = (float*)(base + off);         off = align256(off + (size_t)N * 4);
    float* dinv = (float*)(base + off);        off = align256(off + (size_t)N * 4);
    int* bsum = (int*)(base + off);            off = align256(off + (size_t)NB_SCAN * 4);
    unsigned int* csr = (unsigned int*)(base + off); off = align256(off + (size_t)E * 4);
    float* biasAll = (float*)(base + off);     off = align256(off + 192 * 4);
    __hip_bfloat16* Wt = (__hip_bfloat16*)(base + off); off = align256(off + 192 * 256 * 2);
    unsigned short* hq = (unsigned short*)(base + off); off = align256(off + (size_t)N * 64 * 2);
    unsigned int* hg = (unsigned int*)(base + off);   off = align256(off + (size_t)N * 64 * 4);
    unsigned short* hgi = (unsigned short*)(base + off); off = align256(off + (size_t)N * 64 * 2);

    // zero flag + deg
    hipMemsetAsync(base, 0, zero_end, stream);

    detect_dtype_kernel<<<1, 256, 0, stream>>>((const int*)ei, flag);
    degree_kernel<<<EDGE_GRID, 256, 0, stream>>>(ei, flag, deg);
    scan1_kernel<<<NB_SCAN, 256, 0, stream>>>(deg, bsum);
    scan2_kernel<<<1, 512, 0, stream>>>(bsum);
    scan3_kernel<<<NB_SCAN, 256, 0, stream>>>(deg, bsum, offs, cursor, isq, dinv);
    fill_kernel<<<EDGE_GRID, 256, 0, stream>>>(ei, flag, cursor, csr);
    prep_w_kernel<<<192, 256, 0, stream>>>(Whp, bhp, Wlp, blp, Wi, bi, Wt, biasAll);
    gemm_kernel<<<(N + 63) / 64, 256, 0, stream>>>(x, Wt, biasAll, isq, hq, hg, hgi);
    agg_kernel<<<(N + 3) / 4, 256, 0, stream>>>(hq, hg, hgi, offs, csr, isq, dinv,
                                                w_gh, b_gh, w_gl, b_gl, w_gi, b_gi, out);
}

// Round 10
// 452.071 us; speedup vs baseline: 5.4228x; 1.1661x over previous
//
#include <hip/hip_runtime.h>
#include <hip/hip_bf16.h>

#define N_NODES 100000
#define N_EDGES 3200000
#define IN_DIM  256
#define OUT_DIM 64
#define NB_SCAN ((N_NODES + 255) / 256)   // 391
#define NCLS 4
#define CLS_RANGE 25000                   // 4 * 25000 == 100000 exactly
#define EDGE_GRID 2048                    // 512 blocks per class

typedef __attribute__((ext_vector_type(8))) short short8;
typedef __attribute__((ext_vector_type(4))) float float4v;
typedef __attribute__((ext_vector_type(2))) float floatx2;
typedef __attribute__((ext_vector_type(4))) unsigned int uint4v;

// ---------------------------------------------------------------------------
// fp8 e4m3 pack/unpack (HW cvt on gfx950, software fallback)
// ---------------------------------------------------------------------------
__device__ __forceinline__ unsigned int enc_fp8_sw(float v) {
    unsigned int u = __float_as_uint(v);
    unsigned int s = (u >> 24) & 0x80u;
    unsigned int mag = u & 0x7fffffffu;
    unsigned int q;
    if (mag >= 0x43e00000u) q = 0x7e;
    else if (mag < 0x3c800000u) {
        float av = __uint_as_float(mag);
        q = (unsigned int)(av * 512.0f + 0.5f);
    } else {
        unsigned int mr = mag + 0x00080000u;
        unsigned int e = (mr >> 23) - 127 + 7;
        unsigned int m = (mr >> 20) & 7;
        q = (e << 3) | m;
        if (q > 0x7e) q = 0x7e;
    }
    return s | q;
}
__device__ __forceinline__ float dec_fp8_sw(unsigned int b) {
    unsigned int s = (b & 0x80u) << 24;
    unsigned int e = (b >> 3) & 15u, m = b & 7u;
    float f = (e == 0) ? (float)m * 0.001953125f
                       : __uint_as_float(((e + 120u) << 23) | (m << 20));
    return __uint_as_float(__float_as_uint(f) | s);
}

__device__ __forceinline__ unsigned short pack_fp8x2(float lo, float hi) {
#if __has_builtin(__builtin_amdgcn_cvt_pk_fp8_f32)
    int p = __builtin_amdgcn_cvt_pk_fp8_f32(lo, hi, 0, false);
    return (unsigned short)((unsigned int)p & 0xffffu);
#else
    return (unsigned short)(enc_fp8_sw(lo) | (enc_fp8_sw(hi) << 8));
#endif
}
// decode one 16-bit word (low or high half of w) -> 2 floats; HI is
// compile-time (builtin requires a constant word-select).
template<bool HI>
__device__ __forceinline__ floatx2 cvt2(unsigned int w) {
#if __has_builtin(__builtin_amdgcn_cvt_pk_f32_fp8)
    return __builtin_amdgcn_cvt_pk_f32_fp8((int)w, HI);
#else
    unsigned int g = HI ? (w >> 16) : (w & 0xffffu);
    floatx2 r; r[0] = dec_fp8_sw(g & 0xffu); r[1] = dec_fp8_sw((g >> 8) & 0xffu);
    return r;
#endif
}

// ---------------------------------------------------------------------------
// Kernel 1: detect edge_index dtype (sampled). flag=1 -> int32.
// ---------------------------------------------------------------------------
__global__ void detect_dtype_kernel(const int* __restrict__ ei32, int* __restrict__ flag) {
    int i = threadIdx.x;
    int found = 0;
    for (int w = 2 * i + 1; w < 8192; w += 512)
        found |= (ei32[w] != 0);
    if (found) atomicOr(flag, 1);
}

// ---------------------------------------------------------------------------
// Kernel 1b: normalize edges to int32 ONCE: dst32[] (degree stream) and
// packed edges2[]={src,dst} (fill stream). Later passes re-read these
// L3-resident int32 arrays instead of the (possibly int64) input 8x.
// ---------------------------------------------------------------------------
__global__ __launch_bounds__(256) void convert_kernel(
    const void* __restrict__ ei, const int* __restrict__ flag,
    uint2* __restrict__ edges2, int* __restrict__ dst32) {
    bool is64 = (*flag == 0);
    int i = blockIdx.x * 256 + threadIdx.x;
    int stride = 256 * gridDim.x;
    for (int e = i; e < N_EDGES; e += stride) {
        int s, d;
        if (is64) {
            s = (int)((const long long*)ei)[e];
            d = (int)((const long long*)ei)[N_EDGES + e];
        } else {
            s = ((const int*)ei)[e];
            d = ((const int*)ei)[N_EDGES + e];
        }
        edges2[e] = make_uint2((unsigned)s, (unsigned)d);
        dst32[e] = d;
    }
}

// ---------------------------------------------------------------------------
// Kernel 2: degree count, class-bucketed (c = blockIdx%4 handles dst window of
// 25k nodes; atomic lines stay within <=2 XCD L2s).
// ---------------------------------------------------------------------------
__global__ __launch_bounds__(256) void degree_kernel(
    const int* __restrict__ dst32, int* __restrict__ deg) {
    int c = blockIdx.x & (NCLS - 1);
    int i = (blockIdx.x >> 2) * 256 + threadIdx.x;
    int stride = 256 * (EDGE_GRID / NCLS);
    for (int e = i; e < N_EDGES; e += stride) {
        int d = dst32[e];
        if ((unsigned)d / CLS_RANGE == (unsigned)c)
            atomicAdd(&deg[d], 1);
    }
}

// ---------------------------------------------------------------------------
// Kernels 3a/3b/3c: hierarchical exclusive scan -> offs/cursor/isq/dinv
// ---------------------------------------------------------------------------
__global__ __launch_bounds__(256) void scan1_kernel(const int* __restrict__ deg,
                                                    int* __restrict__ bsum) {
    __shared__ int red[256];
    int tid = threadIdx.x;
    int i = blockIdx.x * 256 + tid;
    int v = (i < N_NODES) ? deg[i] : 0;
    red[tid] = v;
    __syncthreads();
    #pragma unroll
    for (int off = 128; off > 0; off >>= 1) {
        if (tid < off) red[tid] += red[tid + off];
        __syncthreads();
    }
    if (tid == 0) bsum[blockIdx.x] = red[0];
}

__global__ __launch_bounds__(512) void scan2_kernel(int* __restrict__ bsum) {
    __shared__ int sh[512];
    int tid = threadIdx.x;
    int v = (tid < NB_SCAN) ? bsum[tid] : 0;
    sh[tid] = v;
    __syncthreads();
    int val = v;
    #pragma unroll
    for (int off = 1; off < 512; off <<= 1) {
        int t = (tid >= off) ? sh[tid - off] : 0;
        __syncthreads();
        val += t;
        sh[tid] = val;
        __syncthreads();
    }
    if (tid < NB_SCAN) bsum[tid] = val - v;   // exclusive block prefix
}

__global__ __launch_bounds__(256) void scan3_kernel(const int* __restrict__ deg,
                                                    const int* __restrict__ bsum,
                                                    int* __restrict__ offs,
                                                    int* __restrict__ cursor,
                                                    float* __restrict__ isq,
                                                    float* __restrict__ dinv) {
    __shared__ int sh[256];
    int tid = threadIdx.x;
    int i = blockIdx.x * 256 + tid;
    int d = (i < N_NODES) ? deg[i] : 0;
    sh[tid] = d;
    __syncthreads();
    int val = d;
    #pragma unroll
    for (int off = 1; off < 256; off <<= 1) {
        int t = (tid >= off) ? sh[tid - off] : 0;
        __syncthreads();
        val += t;
        sh[tid] = val;
        __syncthreads();
    }
    int ex = bsum[blockIdx.x] + val - d;      // exclusive prefix for node i
    if (i < N_NODES) {
        offs[i] = ex;
        cursor[i] = ex;
        float dr = (float)(d + 1);
        isq[i] = rsqrtf(dr);
        dinv[i] = 1.0f / dr;
    }
    if (i == 0) offs[N_NODES] = N_EDGES;
}

// ---------------------------------------------------------------------------
// Kernel 4: CSR fill, class-bucketed, reading packed int32 edge records.
// ---------------------------------------------------------------------------
__global__ __launch_bounds__(256) void fill_kernel(
    const uint2* __restrict__ edges2,
    int* __restrict__ cursor, unsigned int* __restrict__ csr) {
    int c = blockIdx.x & (NCLS - 1);
    int i = (blockIdx.x >> 2) * 256 + threadIdx.x;
    int stride = 256 * (EDGE_GRID / NCLS);
    for (int e = i; e < N_EDGES; e += stride) {
        uint2 r = edges2[e];
        if (r.y / CLS_RANGE == (unsigned)c) {
            int pos = atomicAdd(&cursor[(int)r.y], 1);
            csr[pos] = r.x;
        }
    }
}

// ---------------------------------------------------------------------------
// Kernel 5: prep weights: Wt[c][k] = bf16(W[k][c]), bias vector biasAll[192].
// ---------------------------------------------------------------------------
__global__ void prep_w_kernel(const float* __restrict__ Whp, const float* __restrict__ bhp,
                              const float* __restrict__ Wlp, const float* __restrict__ blp,
                              const float* __restrict__ Wi,  const float* __restrict__ bi,
                              __hip_bfloat16* __restrict__ Wt, float* __restrict__ biasAll) {
    int c = blockIdx.x;      // 0..191
    int k = threadIdx.x;     // 0..255
    const float* W = (c < 64) ? Whp : (c < 128) ? Wlp : Wi;
    int cl = c & 63;
    Wt[c * 256 + k] = __float2bfloat16(W[k * 64 + cl]);
    if (k == 0) {
        const float* b = (c < 64) ? bhp : (c < 128) ? blp : bi;
        biasAll[c] = b[cl];
    }
}

// ---------------------------------------------------------------------------
// Kernel 6: bf16 MFMA GEMM (unchanged). Writes hq = fp8x2{hp,lp}*isq
// (gather table), hg = bf16x2{hp,lp} unscaled (self), hgi = bf16 i-branch.
// ---------------------------------------------------------------------------
__global__ __launch_bounds__(256) void gemm_kernel(
    const float* __restrict__ x,
    const __hip_bfloat16* __restrict__ Wt,
    const float* __restrict__ biasAll,
    const float* __restrict__ isq,
    unsigned short* __restrict__ hq,
    unsigned int* __restrict__ hg, unsigned short* __restrict__ hgi) {

    __shared__ __align__(16) __hip_bfloat16 xs[64][264];

    const int tid = threadIdx.x;
    const int node0 = blockIdx.x * 64;
    const int w = tid >> 6;
    const int lane = tid & 63;
    const int cl = lane & 15;
    const int kh = lane >> 4;

    short8 B[3][8];
    #pragma unroll
    for (int s = 0; s < 3; ++s) {
        const __hip_bfloat16* wp = Wt + (16 * w + 64 * s + cl) * 256 + kh * 8;
        #pragma unroll
        for (int ks = 0; ks < 8; ++ks)
            B[s][ks] = *(const short8*)(wp + ks * 32);
    }

    #pragma unroll
    for (int j = 0; j < 16; ++j) {
        int f = j * 1024 + tid * 4;
        int rr = f >> 8, cc = f & 255;
        float4v v = {0.f, 0.f, 0.f, 0.f};
        int node = node0 + rr;
        if (node < N_NODES)
            v = *(const float4v*)(x + (size_t)node * 256 + cc);
        __hip_bfloat16 b0 = __float2bfloat16(v.x), b1 = __float2bfloat16(v.y);
        __hip_bfloat16 b2 = __float2bfloat16(v.z), b3 = __float2bfloat16(v.w);
        unsigned int lo = (unsigned int)*(unsigned short*)&b0 | ((unsigned int)*(unsigned short*)&b1 << 16);
        unsigned int hi = (unsigned int)*(unsigned short*)&b2 | ((unsigned int)*(unsigned short*)&b3 << 16);
        unsigned int* dst = (unsigned int*)&xs[rr][cc];
        dst[0] = lo; dst[1] = hi;
    }
    __syncthreads();

    float4v acc[4][3];
    #pragma unroll
    for (int rt = 0; rt < 4; ++rt)
        #pragma unroll
        for (int s = 0; s < 3; ++s)
            acc[rt][s] = (float4v){0.f, 0.f, 0.f, 0.f};

    const char* xbase = (const char*)&xs[0][0];
    #pragma unroll
    for (int ks = 0; ks < 8; ++ks) {
        short8 A[4];
        #pragma unroll
        for (int rt = 0; rt < 4; ++rt)
            A[rt] = *(const short8*)(xbase + (size_t)(rt * 16 + cl) * 528 + ks * 64 + kh * 16);
        #pragma unroll
        for (int rt = 0; rt < 4; ++rt)
            #pragma unroll
            for (int s = 0; s < 3; ++s)
                acc[rt][s] = __builtin_amdgcn_mfma_f32_16x16x32_bf16(A[rt], B[s][ks], acc[rt][s], 0, 0, 0);
    }

    const int c0 = 16 * w + cl;
    const float bias_hp = biasAll[c0];
    const float bias_lp = biasAll[c0 + 64];
    const float bias_i  = biasAll[c0 + 128];

    #pragma unroll
    for (int rt = 0; rt < 4; ++rt) {
        #pragma unroll
        for (int r = 0; r < 4; ++r) {
            int node = node0 + rt * 16 + kh * 4 + r;
            if (node >= N_NODES) continue;
            float sq = isq[node];
            float vhp = acc[rt][0][r] + bias_hp;
            float vlp = acc[rt][1][r] + bias_lp;
            float vi  = acc[rt][2][r] + bias_i;
            hq[(size_t)node * 64 + c0] = pack_fp8x2(vhp * sq, vlp * sq);
            __hip_bfloat16 bh = __float2bfloat16(vhp);
            __hip_bfloat16 bl = __float2bfloat16(vlp);
            __hip_bfloat16 bb = __float2bfloat16(vi);
            hg[(size_t)node * 64 + c0] =
                (unsigned int)*(unsigned short*)&bh | ((unsigned int)*(unsigned short*)&bl << 16);
            hgi[(size_t)node * 64 + c0] = *(unsigned short*)&bb;
        }
    }
}

// ---------------------------------------------------------------------------
// Kernel 7: fused aggregation + gates + log_softmax, v2.
// Wave per node; 8 neighbors per iteration: lane = (slot=lane>>3, oct=lane&7).
// Each lane: ONE dwordx4 (16B = 8 fp8x2 features) per slot-neighbor. Per-wave
// LDS transpose maps octet partials back to lane=feature at the end.
// ---------------------------------------------------------------------------
__device__ __forceinline__ float wave_sum(float x) {
    #pragma unroll
    for (int off = 32; off > 0; off >>= 1) x += __shfl_xor(x, off);
    return x;
}
__device__ __forceinline__ float wave_max(float x) {
    #pragma unroll
    for (int off = 32; off > 0; off >>= 1) x = fmaxf(x, __shfl_xor(x, off));
    return x;
}

__global__ __launch_bounds__(256) void agg_kernel(
    const unsigned short* __restrict__ hq,
    const unsigned int* __restrict__ hg,
    const unsigned short* __restrict__ hgi,
    const int* __restrict__ offs,
    const unsigned int* __restrict__ csr,
    const float* __restrict__ isq,
    const float* __restrict__ dinv,
    const float* __restrict__ w_gh, const float* __restrict__ b_gh,
    const float* __restrict__ w_gl, const float* __restrict__ b_gl,
    const float* __restrict__ w_gi, const float* __restrict__ b_gi,
    float* __restrict__ out) {
    __shared__ float2 xf[4][8 * 65];          // per-wave transpose scratch

    int wid = threadIdx.x >> 6;
    int v = blockIdx.x * 4 + wid;
    int lane = threadIdx.x & 63;
    if (v >= N_NODES) return;

    int start = offs[v], end = offs[v + 1];
    const int slot = lane >> 3;               // neighbor slot 0..7
    const int oct  = lane & 7;                // feature octet 0..7
    const char* hqB = (const char*)hq;

    float ahp[8], alp[8];
    #pragma unroll
    for (int j = 0; j < 8; ++j) { ahp[j] = 0.f; alp[j] = 0.f; }

    for (int j0 = start; j0 < end; j0 += 64) {
        int m = end - j0; if (m > 64) m = 64;
        unsigned int uu = 0;
        if (lane < m) uu = csr[j0 + lane];
        for (int k0 = 0; k0 < m; k0 += 8) {
            int idx = k0 + slot;
            bool valid = idx < m;
            int idxc = valid ? idx : (m - 1);
            unsigned int u = __shfl(uu, idxc);
            uint4v g = *(const uint4v*)(hqB + (size_t)u * 128 + oct * 16);
            unsigned int zm = valid ? 0xffffffffu : 0u;
            #pragma unroll
            for (int dd = 0; dd < 4; ++dd) {
                unsigned int wv = g[dd] & zm;
                floatx2 e0 = cvt2<false>(wv);
                floatx2 e1 = cvt2<true>(wv);
                ahp[2 * dd]     += e0[0]; alp[2 * dd]     += e0[1];
                ahp[2 * dd + 1] += e1[0]; alp[2 * dd + 1] += e1[1];
            }
        }
    }

    // transpose: slot-partials -> lane=feature. feature f = 8*oct + j,
    // summed over 8 slots. xf index = slot*65 + oct*8 + j  (+pad vs conflicts)
    #pragma unroll
    for (int j = 0; j < 8; ++j)
        xf[wid][slot * 65 + oct * 8 + j] = make_float2(ahp[j], alp[j]);
    float acc_hp = 0.f, acc_lp = 0.f;
    #pragma unroll
    for (int s = 0; s < 8; ++s) {
        float2 t = xf[wid][s * 65 + lane];
        acc_hp += t.x; acc_lp += t.y;
    }

    float isqv = isq[v];
    float agg_hp = acc_hp * isqv;
    float agg_lp = acc_lp * isqv;

    unsigned int gv = hg[(size_t)v * 64 + lane];
    float hhp = __uint_as_float(gv << 16);
    float hlp = __uint_as_float(gv & 0xffff0000u);
    float hi  = __uint_as_float((unsigned int)hgi[(size_t)v * 64 + lane] << 16);

    float dv = dinv[v];
    float Hhp = fmaxf(hhp - (agg_hp + dv * hhp), 0.f);
    float Hlp = fmaxf(agg_lp + dv * hlp, 0.f);
    float Hi  = fmaxf(hi, 0.f);

    float sh = wave_sum(Hhp * w_gh[lane]) + b_gh[0];
    float sl = wave_sum(Hlp * w_gl[lane]) + b_gl[0];
    float si = wave_sum(Hi  * w_gi[lane]) + b_gi[0];

    float o = sh * Hhp + sl * Hlp + si * Hi;
    float mx = wave_max(o);
    float se = wave_sum(expf(o - mx));
    out[(size_t)v * 64 + lane] = o - mx - logf(se);
}

// ---------------------------------------------------------------------------
static inline size_t align256(size_t v) { return (v + 255) & ~(size_t)255; }

extern "C" void kernel_launch(void* const* d_in, const int* in_sizes, int n_in,
                              void* d_out, int out_size, void* d_ws, size_t ws_size,
                              hipStream_t stream) {
    const float* x    = (const float*)d_in[0];
    const void*  ei   = d_in[1];
    const float* Whp  = (const float*)d_in[2];
    const float* bhp  = (const float*)d_in[3];
    const float* Wlp  = (const float*)d_in[4];
    const float* blp  = (const float*)d_in[5];
    const float* Wi   = (const float*)d_in[6];
    const float* bi   = (const float*)d_in[7];
    const float* w_gh = (const float*)d_in[8];
    const float* b_gh = (const float*)d_in[9];
    const float* w_gl = (const float*)d_in[10];
    const float* b_gl = (const float*)d_in[11];
    const float* w_gi = (const float*)d_in[12];
    const float* b_gi = (const float*)d_in[13];
    float* out = (float*)d_out;

    const int N = N_NODES, E = N_EDGES;

    // workspace layout (256B-aligned regions)
    char* base = (char*)d_ws;
    size_t off = 0;
    int* flag = (int*)(base + off);            off = align256(off + sizeof(int));
    int* deg = (int*)(base + off);             off = align256(off + (size_t)N * 4);
    size_t zero_end = off;                     // memset covers [0, zero_end)
    int* offs = (int*)(base + off);            off = align256(off + (size_t)(N + 1) * 4);
    int* cursor = (int*)(base + off);          off = align256(off + (size_t)N * 4);
    float* isq = (float*)(base + off);         off = align256(off + (size_t)N * 4);
    float* dinv = (float*)(base + off);        off = align256(off + (size_t)N * 4);
    int* bsum = (int*)(base + off);            off = align256(off + (size_t)NB_SCAN * 4);
    uint2* edges2 = (uint2*)(base + off);      off = align256(off + (size_t)E * 8);
    int* dst32 = (int*)(base + off);           off = align256(off + (size_t)E * 4);
    unsigned int* csr = (unsigned int*)(base + off); off = align256(off + (size_t)E * 4);
    float* biasAll = (float*)(base + off);     off = align256(off + 192 * 4);
    __hip_bfloat16* Wt = (__hip_bfloat16*)(base + off); off = align256(off + 192 * 256 * 2);
    unsigned short* hq = (unsigned short*)(base + off); off = align256(off + (size_t)N * 64 * 2);
    unsigned int* hg = (unsigned int*)(base + off);   off = align256(off + (size_t)N * 64 * 4);
    unsigned short* hgi = (unsigned short*)(base + off); off = align256(off + (size_t)N * 64 * 2);

    // zero flag + deg
    (void)hipMemsetAsync(base, 0, zero_end, stream);

    detect_dtype_kernel<<<1, 256, 0, stream>>>((const int*)ei, flag);
    convert_kernel<<<2048, 256, 0, stream>>>(ei, flag, edges2, dst32);
    degree_kernel<<<EDGE_GRID, 256, 0, stream>>>(dst32, deg);
    scan1_kernel<<<NB_SCAN, 256, 0, stream>>>(deg, bsum);
    scan2_kernel<<<1, 512, 0, stream>>>(bsum);
    scan3_kernel<<<NB_SCAN, 256, 0, stream>>>(deg, bsum, offs, cursor, isq, dinv);
    fill_kernel<<<EDGE_GRID, 256, 0, stream>>>(edges2, cursor, csr);
    prep_w_kernel<<<192, 256, 0, stream>>>(Whp, bhp, Wlp, blp, Wi, bi, Wt, biasAll);
    gemm_kernel<<<(N + 63) / 64, 256, 0, stream>>>(x, Wt, biasAll, isq, hq, hg, hgi);
    agg_kernel<<<(N + 3) / 4, 256, 0, stream>>>(hq, hg, hgi, offs, csr, isq, dinv,
                                                w_gh, b_gh, w_gl, b_gl, w_gi, b_gi, out);
}

// Round 11
// 438.668 us; speedup vs baseline: 5.5885x; 1.0306x over previous
//
#include <hip/hip_runtime.h>
#include <hip/hip_bf16.h>

#define N_NODES 100000
#define N_EDGES 3200000
#define IN_DIM  256
#define OUT_DIM 64
#define NB_SCAN ((N_NODES + 255) / 256)   // 391
#define NCLS 8
#define CLS_RANGE 12500                   // 8 * 12500 == 100000 exactly
#define EDGE_GRID 2048                    // 256 blocks per class

typedef __attribute__((ext_vector_type(8))) short short8;
typedef __attribute__((ext_vector_type(4))) float float4v;
typedef __attribute__((ext_vector_type(2))) float floatx2;
typedef __attribute__((ext_vector_type(4))) unsigned int uint4v;

// ---------------------------------------------------------------------------
// fp8 e4m3 pack/unpack (HW cvt on gfx950, software fallback)
// ---------------------------------------------------------------------------
__device__ __forceinline__ unsigned int enc_fp8_sw(float v) {
    unsigned int u = __float_as_uint(v);
    unsigned int s = (u >> 24) & 0x80u;
    unsigned int mag = u & 0x7fffffffu;
    unsigned int q;
    if (mag >= 0x43e00000u) q = 0x7e;
    else if (mag < 0x3c800000u) {
        float av = __uint_as_float(mag);
        q = (unsigned int)(av * 512.0f + 0.5f);
    } else {
        unsigned int mr = mag + 0x00080000u;
        unsigned int e = (mr >> 23) - 127 + 7;
        unsigned int m = (mr >> 20) & 7;
        q = (e << 3) | m;
        if (q > 0x7e) q = 0x7e;
    }
    return s | q;
}
__device__ __forceinline__ float dec_fp8_sw(unsigned int b) {
    unsigned int s = (b & 0x80u) << 24;
    unsigned int e = (b >> 3) & 15u, m = b & 7u;
    float f = (e == 0) ? (float)m * 0.001953125f
                       : __uint_as_float(((e + 120u) << 23) | (m << 20));
    return __uint_as_float(__float_as_uint(f) | s);
}

__device__ __forceinline__ unsigned short pack_fp8x2(float lo, float hi) {
#if __has_builtin(__builtin_amdgcn_cvt_pk_fp8_f32)
    int p = __builtin_amdgcn_cvt_pk_fp8_f32(lo, hi, 0, false);
    return (unsigned short)((unsigned int)p & 0xffffu);
#else
    return (unsigned short)(enc_fp8_sw(lo) | (enc_fp8_sw(hi) << 8));
#endif
}
// decode one 16-bit word (low or high half of w) -> 2 floats; HI is
// compile-time (builtin requires a constant word-select).
template<bool HI>
__device__ __forceinline__ floatx2 cvt2(unsigned int w) {
#if __has_builtin(__builtin_amdgcn_cvt_pk_f32_fp8)
    return __builtin_amdgcn_cvt_pk_f32_fp8((int)w, HI);
#else
    unsigned int g = HI ? (w >> 16) : (w & 0xffffu);
    floatx2 r; r[0] = dec_fp8_sw(g & 0xffu); r[1] = dec_fp8_sw((g >> 8) & 0xffu);
    return r;
#endif
}

// ---------------------------------------------------------------------------
// Kernel 1: detect edge_index dtype (sampled). flag=1 -> int32.
// ---------------------------------------------------------------------------
__global__ void detect_dtype_kernel(const int* __restrict__ ei32, int* __restrict__ flag) {
    int i = threadIdx.x;
    int found = 0;
    for (int w = 2 * i + 1; w < 8192; w += 512)
        found |= (ei32[w] != 0);
    if (found) atomicOr(flag, 1);
}

// ---------------------------------------------------------------------------
// Kernel 1b: normalize edges to int32 ONCE: dst32[] (degree stream) and
// packed edges2[]={src,dst} (fill stream). Later passes re-read these
// L3-resident int32 arrays instead of the (possibly int64) input 8x.
// ---------------------------------------------------------------------------
__global__ __launch_bounds__(256) void convert_kernel(
    const void* __restrict__ ei, const int* __restrict__ flag,
    uint2* __restrict__ edges2, int* __restrict__ dst32) {
    bool is64 = (*flag == 0);
    int i = blockIdx.x * 256 + threadIdx.x;
    int stride = 256 * gridDim.x;
    for (int e = i; e < N_EDGES; e += stride) {
        int s, d;
        if (is64) {
            s = (int)((const long long*)ei)[e];
            d = (int)((const long long*)ei)[N_EDGES + e];
        } else {
            s = ((const int*)ei)[e];
            d = ((const int*)ei)[N_EDGES + e];
        }
        edges2[e] = make_uint2((unsigned)s, (unsigned)d);
        dst32[e] = d;
    }
}

// ---------------------------------------------------------------------------
// Kernel 2: degree count, XCD-bucketed: class c = blockIdx%8 handles only dst
// in [c*12500,(c+1)*12500) -> 50KB atomic window stays in XCD-c's L2.
// ---------------------------------------------------------------------------
__global__ __launch_bounds__(256) void degree_kernel(
    const int* __restrict__ dst32, int* __restrict__ deg) {
    int c = blockIdx.x & (NCLS - 1);
    int i = (blockIdx.x >> 3) * 256 + threadIdx.x;
    int stride = 256 * (EDGE_GRID / NCLS);
    for (int e = i; e < N_EDGES; e += stride) {
        int d = dst32[e];
        if ((unsigned)d / CLS_RANGE == (unsigned)c)
            atomicAdd(&deg[d], 1);
    }
}

// ---------------------------------------------------------------------------
// Kernels 3a/3b/3c: hierarchical exclusive scan -> offs/cursor/isq/dinv
// ---------------------------------------------------------------------------
__global__ __launch_bounds__(256) void scan1_kernel(const int* __restrict__ deg,
                                                    int* __restrict__ bsum) {
    __shared__ int red[256];
    int tid = threadIdx.x;
    int i = blockIdx.x * 256 + tid;
    int v = (i < N_NODES) ? deg[i] : 0;
    red[tid] = v;
    __syncthreads();
    #pragma unroll
    for (int off = 128; off > 0; off >>= 1) {
        if (tid < off) red[tid] += red[tid + off];
        __syncthreads();
    }
    if (tid == 0) bsum[blockIdx.x] = red[0];
}

__global__ __launch_bounds__(512) void scan2_kernel(int* __restrict__ bsum) {
    __shared__ int sh[512];
    int tid = threadIdx.x;
    int v = (tid < NB_SCAN) ? bsum[tid] : 0;
    sh[tid] = v;
    __syncthreads();
    int val = v;
    #pragma unroll
    for (int off = 1; off < 512; off <<= 1) {
        int t = (tid >= off) ? sh[tid - off] : 0;
        __syncthreads();
        val += t;
        sh[tid] = val;
        __syncthreads();
    }
    if (tid < NB_SCAN) bsum[tid] = val - v;   // exclusive block prefix
}

__global__ __launch_bounds__(256) void scan3_kernel(const int* __restrict__ deg,
                                                    const int* __restrict__ bsum,
                                                    int* __restrict__ offs,
                                                    int* __restrict__ cursor,
                                                    float* __restrict__ isq,
                                                    float* __restrict__ dinv) {
    __shared__ int sh[256];
    int tid = threadIdx.x;
    int i = blockIdx.x * 256 + tid;
    int d = (i < N_NODES) ? deg[i] : 0;
    sh[tid] = d;
    __syncthreads();
    int val = d;
    #pragma unroll
    for (int off = 1; off < 256; off <<= 1) {
        int t = (tid >= off) ? sh[tid - off] : 0;
        __syncthreads();
        val += t;
        sh[tid] = val;
        __syncthreads();
    }
    int ex = bsum[blockIdx.x] + val - d;      // exclusive prefix for node i
    if (i < N_NODES) {
        offs[i] = ex;
        cursor[i] = ex;
        float dr = (float)(d + 1);
        isq[i] = rsqrtf(dr);
        dinv[i] = 1.0f / dr;
    }
    if (i == 0) offs[N_NODES] = N_EDGES;
}

// ---------------------------------------------------------------------------
// Kernel 4: CSR fill, XCD-bucketed: class c's cursor window (50KB) and csr
// window (~1.6MB) stay in XCD-c's L2 -> each line written back once, full.
// ---------------------------------------------------------------------------
__global__ __launch_bounds__(256) void fill_kernel(
    const uint2* __restrict__ edges2,
    int* __restrict__ cursor, unsigned int* __restrict__ csr) {
    int c = blockIdx.x & (NCLS - 1);
    int i = (blockIdx.x >> 3) * 256 + threadIdx.x;
    int stride = 256 * (EDGE_GRID / NCLS);
    for (int e = i; e < N_EDGES; e += stride) {
        uint2 r = edges2[e];
        if (r.y / CLS_RANGE == (unsigned)c) {
            int pos = atomicAdd(&cursor[(int)r.y], 1);
            csr[pos] = r.x;
        }
    }
}

// ---------------------------------------------------------------------------
// Kernel 5: prep weights: Wt[c][k] = bf16(W[k][c]), bias vector biasAll[192].
// ---------------------------------------------------------------------------
__global__ void prep_w_kernel(const float* __restrict__ Whp, const float* __restrict__ bhp,
                              const float* __restrict__ Wlp, const float* __restrict__ blp,
                              const float* __restrict__ Wi,  const float* __restrict__ bi,
                              __hip_bfloat16* __restrict__ Wt, float* __restrict__ biasAll) {
    int c = blockIdx.x;      // 0..191
    int k = threadIdx.x;     // 0..255
    const float* W = (c < 64) ? Whp : (c < 128) ? Wlp : Wi;
    int cl = c & 63;
    Wt[c * 256 + k] = __float2bfloat16(W[k * 64 + cl]);
    if (k == 0) {
        const float* b = (c < 64) ? bhp : (c < 128) ? blp : bi;
        biasAll[c] = b[cl];
    }
}

// ---------------------------------------------------------------------------
// Kernel 6: bf16 MFMA GEMM (unchanged). Writes hq = fp8x2{hp,lp}*isq
// (gather table), hg = bf16x2{hp,lp} unscaled (self), hgi = bf16 i-branch.
// ---------------------------------------------------------------------------
__global__ __launch_bounds__(256) void gemm_kernel(
    const float* __restrict__ x,
    const __hip_bfloat16* __restrict__ Wt,
    const float* __restrict__ biasAll,
    const float* __restrict__ isq,
    unsigned short* __restrict__ hq,
    unsigned int* __restrict__ hg, unsigned short* __restrict__ hgi) {

    __shared__ __align__(16) __hip_bfloat16 xs[64][264];

    const int tid = threadIdx.x;
    const int node0 = blockIdx.x * 64;
    const int w = tid >> 6;
    const int lane = tid & 63;
    const int cl = lane & 15;
    const int kh = lane >> 4;

    short8 B[3][8];
    #pragma unroll
    for (int s = 0; s < 3; ++s) {
        const __hip_bfloat16* wp = Wt + (16 * w + 64 * s + cl) * 256 + kh * 8;
        #pragma unroll
        for (int ks = 0; ks < 8; ++ks)
            B[s][ks] = *(const short8*)(wp + ks * 32);
    }

    #pragma unroll
    for (int j = 0; j < 16; ++j) {
        int f = j * 1024 + tid * 4;
        int rr = f >> 8, cc = f & 255;
        float4v v = {0.f, 0.f, 0.f, 0.f};
        int node = node0 + rr;
        if (node < N_NODES)
            v = *(const float4v*)(x + (size_t)node * 256 + cc);
        __hip_bfloat16 b0 = __float2bfloat16(v.x), b1 = __float2bfloat16(v.y);
        __hip_bfloat16 b2 = __float2bfloat16(v.z), b3 = __float2bfloat16(v.w);
        unsigned int lo = (unsigned int)*(unsigned short*)&b0 | ((unsigned int)*(unsigned short*)&b1 << 16);
        unsigned int hi = (unsigned int)*(unsigned short*)&b2 | ((unsigned int)*(unsigned short*)&b3 << 16);
        unsigned int* dst = (unsigned int*)&xs[rr][cc];
        dst[0] = lo; dst[1] = hi;
    }
    __syncthreads();

    float4v acc[4][3];
    #pragma unroll
    for (int rt = 0; rt < 4; ++rt)
        #pragma unroll
        for (int s = 0; s < 3; ++s)
            acc[rt][s] = (float4v){0.f, 0.f, 0.f, 0.f};

    const char* xbase = (const char*)&xs[0][0];
    #pragma unroll
    for (int ks = 0; ks < 8; ++ks) {
        short8 A[4];
        #pragma unroll
        for (int rt = 0; rt < 4; ++rt)
            A[rt] = *(const short8*)(xbase + (size_t)(rt * 16 + cl) * 528 + ks * 64 + kh * 16);
        #pragma unroll
        for (int rt = 0; rt < 4; ++rt)
            #pragma unroll
            for (int s = 0; s < 3; ++s)
                acc[rt][s] = __builtin_amdgcn_mfma_f32_16x16x32_bf16(A[rt], B[s][ks], acc[rt][s], 0, 0, 0);
    }

    const int c0 = 16 * w + cl;
    const float bias_hp = biasAll[c0];
    const float bias_lp = biasAll[c0 + 64];
    const float bias_i  = biasAll[c0 + 128];

    #pragma unroll
    for (int rt = 0; rt < 4; ++rt) {
        #pragma unroll
        for (int r = 0; r < 4; ++r) {
            int node = node0 + rt * 16 + kh * 4 + r;
            if (node >= N_NODES) continue;
            float sq = isq[node];
            float vhp = acc[rt][0][r] + bias_hp;
            float vlp = acc[rt][1][r] + bias_lp;
            float vi  = acc[rt][2][r] + bias_i;
            hq[(size_t)node * 64 + c0] = pack_fp8x2(vhp * sq, vlp * sq);
            __hip_bfloat16 bh = __float2bfloat16(vhp);
            __hip_bfloat16 bl = __float2bfloat16(vlp);
            __hip_bfloat16 bb = __float2bfloat16(vi);
            hg[(size_t)node * 64 + c0] =
                (unsigned int)*(unsigned short*)&bh | ((unsigned int)*(unsigned short*)&bl << 16);
            hgi[(size_t)node * 64 + c0] = *(unsigned short*)&bb;
        }
    }
}

// ---------------------------------------------------------------------------
// Kernel 7: fused aggregation + gates + log_softmax, v2 (unchanged from r10).
// Wave per node; 8 neighbors per iteration: lane = (slot=lane>>3, oct=lane&7).
// Each lane: ONE dwordx4 (16B = 8 fp8x2 features) per slot-neighbor. Per-wave
// LDS transpose maps octet partials back to lane=feature at the end.
// ---------------------------------------------------------------------------
__device__ __forceinline__ float wave_sum(float x) {
    #pragma unroll
    for (int off = 32; off > 0; off >>= 1) x += __shfl_xor(x, off);
    return x;
}
__device__ __forceinline__ float wave_max(float x) {
    #pragma unroll
    for (int off = 32; off > 0; off >>= 1) x = fmaxf(x, __shfl_xor(x, off));
    return x;
}

__global__ __launch_bounds__(256) void agg_kernel(
    const unsigned short* __restrict__ hq,
    const unsigned int* __restrict__ hg,
    const unsigned short* __restrict__ hgi,
    const int* __restrict__ offs,
    const unsigned int* __restrict__ csr,
    const float* __restrict__ isq,
    const float* __restrict__ dinv,
    const float* __restrict__ w_gh, const float* __restrict__ b_gh,
    const float* __restrict__ w_gl, const float* __restrict__ b_gl,
    const float* __restrict__ w_gi, const float* __restrict__ b_gi,
    float* __restrict__ out) {
    __shared__ float2 xf[4][8 * 65];          // per-wave transpose scratch

    int wid = threadIdx.x >> 6;
    int v = blockIdx.x * 4 + wid;
    int lane = threadIdx.x & 63;
    if (v >= N_NODES) return;

    int start = offs[v], end = offs[v + 1];
    const int slot = lane >> 3;               // neighbor slot 0..7
    const int oct  = lane & 7;                // feature octet 0..7
    const char* hqB = (const char*)hq;

    float ahp[8], alp[8];
    #pragma unroll
    for (int j = 0; j < 8; ++j) { ahp[j] = 0.f; alp[j] = 0.f; }

    for (int j0 = start; j0 < end; j0 += 64) {
        int m = end - j0; if (m > 64) m = 64;
        unsigned int uu = 0;
        if (lane < m) uu = csr[j0 + lane];
        for (int k0 = 0; k0 < m; k0 += 8) {
            int idx = k0 + slot;
            bool valid = idx < m;
            int idxc = valid ? idx : (m - 1);
            unsigned int u = __shfl(uu, idxc);
            uint4v g = *(const uint4v*)(hqB + (size_t)u * 128 + oct * 16);
            unsigned int zm = valid ? 0xffffffffu : 0u;
            #pragma unroll
            for (int dd = 0; dd < 4; ++dd) {
                unsigned int wv = g[dd] & zm;
                floatx2 e0 = cvt2<false>(wv);
                floatx2 e1 = cvt2<true>(wv);
                ahp[2 * dd]     += e0[0]; alp[2 * dd]     += e0[1];
                ahp[2 * dd + 1] += e1[0]; alp[2 * dd + 1] += e1[1];
            }
        }
    }

    // transpose: slot-partials -> lane=feature. feature f = 8*oct + j,
    // summed over 8 slots. xf index = slot*65 + oct*8 + j  (+pad vs conflicts)
    #pragma unroll
    for (int j = 0; j < 8; ++j)
        xf[wid][slot * 65 + oct * 8 + j] = make_float2(ahp[j], alp[j]);
    float acc_hp = 0.f, acc_lp = 0.f;
    #pragma unroll
    for (int s = 0; s < 8; ++s) {
        float2 t = xf[wid][s * 65 + lane];
        acc_hp += t.x; acc_lp += t.y;
    }

    float isqv = isq[v];
    float agg_hp = acc_hp * isqv;
    float agg_lp = acc_lp * isqv;

    unsigned int gv = hg[(size_t)v * 64 + lane];
    float hhp = __uint_as_float(gv << 16);
    float hlp = __uint_as_float(gv & 0xffff0000u);
    float hi  = __uint_as_float((unsigned int)hgi[(size_t)v * 64 + lane] << 16);

    float dv = dinv[v];
    float Hhp = fmaxf(hhp - (agg_hp + dv * hhp), 0.f);
    float Hlp = fmaxf(agg_lp + dv * hlp, 0.f);
    float Hi  = fmaxf(hi, 0.f);

    float sh = wave_sum(Hhp * w_gh[lane]) + b_gh[0];
    float sl = wave_sum(Hlp * w_gl[lane]) + b_gl[0];
    float si = wave_sum(Hi  * w_gi[lane]) + b_gi[0];

    float o = sh * Hhp + sl * Hlp + si * Hi;
    float mx = wave_max(o);
    float se = wave_sum(expf(o - mx));
    out[(size_t)v * 64 + lane] = o - mx - logf(se);
}

// ---------------------------------------------------------------------------
static inline size_t align256(size_t v) { return (v + 255) & ~(size_t)255; }

extern "C" void kernel_launch(void* const* d_in, const int* in_sizes, int n_in,
                              void* d_out, int out_size, void* d_ws, size_t ws_size,
                              hipStream_t stream) {
    const float* x    = (const float*)d_in[0];
    const void*  ei   = d_in[1];
    const float* Whp  = (const float*)d_in[2];
    const float* bhp  = (const float*)d_in[3];
    const float* Wlp  = (const float*)d_in[4];
    const float* blp  = (const float*)d_in[5];
    const float* Wi   = (const float*)d_in[6];
    const float* bi   = (const float*)d_in[7];
    const float* w_gh = (const float*)d_in[8];
    const float* b_gh = (const float*)d_in[9];
    const float* w_gl = (const float*)d_in[10];
    const float* b_gl = (const float*)d_in[11];
    const float* w_gi = (const float*)d_in[12];
    const float* b_gi = (const float*)d_in[13];
    float* out = (float*)d_out;

    const int N = N_NODES, E = N_EDGES;

    // workspace layout (256B-aligned regions)
    char* base = (char*)d_ws;
    size_t off = 0;
    int* flag = (int*)(base + off);            off = align256(off + sizeof(int));
    int* deg = (int*)(base + off);             off = align256(off + (size_t)N * 4);
    size_t zero_end = off;                     // memset covers [0, zero_end)
    int* offs = (int*)(base + off);            off = align256(off + (size_t)(N + 1) * 4);
    int* cursor = (int*)(base + off);          off = align256(off + (size_t)N * 4);
    float* isq = (float*)(base + off);         off = align256(off + (size_t)N * 4);
    float* dinv = (float*)(base + off);        off = align256(off + (size_t)N * 4);
    int* bsum = (int*)(base + off);            off = align256(off + (size_t)NB_SCAN * 4);
    uint2* edges2 = (uint2*)(base + off);      off = align256(off + (size_t)E * 8);
    int* dst32 = (int*)(base + off);           off = align256(off + (size_t)E * 4);
    unsigned int* csr = (unsigned int*)(base + off); off = align256(off + (size_t)E * 4);
    float* biasAll = (float*)(base + off);     off = align256(off + 192 * 4);
    __hip_bfloat16* Wt = (__hip_bfloat16*)(base + off); off = align256(off + 192 * 256 * 2);
    unsigned short* hq = (unsigned short*)(base + off); off = align256(off + (size_t)N * 64 * 2);
    unsigned int* hg = (unsigned int*)(base + off);   off = align256(off + (size_t)N * 64 * 4);
    unsigned short* hgi = (unsigned short*)(base + off); off = align256(off + (size_t)N * 64 * 2);

    // zero flag + deg
    (void)hipMemsetAsync(base, 0, zero_end, stream);

    detect_dtype_kernel<<<1, 256, 0, stream>>>((const int*)ei, flag);
    convert_kernel<<<2048, 256, 0, stream>>>(ei, flag, edges2, dst32);
    degree_kernel<<<EDGE_GRID, 256, 0, stream>>>(dst32, deg);
    scan1_kernel<<<NB_SCAN, 256, 0, stream>>>(deg, bsum);
    scan2_kernel<<<1, 512, 0, stream>>>(bsum);
    scan3_kernel<<<NB_SCAN, 256, 0, stream>>>(deg, bsum, offs, cursor, isq, dinv);
    fill_kernel<<<EDGE_GRID, 256, 0, stream>>>(edges2, cursor, csr);
    prep_w_kernel<<<192, 256, 0, stream>>>(Whp, bhp, Wlp, blp, Wi, bi, Wt, biasAll);
    gemm_kernel<<<(N + 63) / 64, 256, 0, stream>>>(x, Wt, biasAll, isq, hq, hg, hgi);
    agg_kernel<<<(N + 3) / 4, 256, 0, stream>>>(hq, hg, hgi, offs, csr, isq, dinv,
                                                w_gh, b_gh, w_gl, b_gl, w_gi, b_gi, out);
}

// Round 12
// 438.036 us; speedup vs baseline: 5.5966x; 1.0014x over previous
//
#include <hip/hip_runtime.h>
#include <hip/hip_bf16.h>

#define N_NODES 100000
#define N_EDGES 3200000
#define IN_DIM  256
#define OUT_DIM 64
#define NB_SCAN ((N_NODES + 255) / 256)   // 391
#define NCLS 8
#define CLS_RANGE 12500                   // 8 * 12500 == 100000 exactly
#define EDGE_GRID 2048                    // hist/bin grid; 256 blocks/class in degree/fill
#define NHIST (NCLS * EDGE_GRID)          // 16384

typedef __attribute__((ext_vector_type(8))) short short8;
typedef __attribute__((ext_vector_type(4))) float float4v;
typedef __attribute__((ext_vector_type(2))) float floatx2;
typedef __attribute__((ext_vector_type(4))) unsigned int uint4v;

// ---------------------------------------------------------------------------
// fp8 e4m3 pack/unpack (HW cvt on gfx950, software fallback)
// ---------------------------------------------------------------------------
__device__ __forceinline__ unsigned int enc_fp8_sw(float v) {
    unsigned int u = __float_as_uint(v);
    unsigned int s = (u >> 24) & 0x80u;
    unsigned int mag = u & 0x7fffffffu;
    unsigned int q;
    if (mag >= 0x43e00000u) q = 0x7e;
    else if (mag < 0x3c800000u) {
        float av = __uint_as_float(mag);
        q = (unsigned int)(av * 512.0f + 0.5f);
    } else {
        unsigned int mr = mag + 0x00080000u;
        unsigned int e = (mr >> 23) - 127 + 7;
        unsigned int m = (mr >> 20) & 7;
        q = (e << 3) | m;
        if (q > 0x7e) q = 0x7e;
    }
    return s | q;
}
__device__ __forceinline__ float dec_fp8_sw(unsigned int b) {
    unsigned int s = (b & 0x80u) << 24;
    unsigned int e = (b >> 3) & 15u, m = b & 7u;
    float f = (e == 0) ? (float)m * 0.001953125f
                       : __uint_as_float(((e + 120u) << 23) | (m << 20));
    return __uint_as_float(__float_as_uint(f) | s);
}

__device__ __forceinline__ unsigned short pack_fp8x2(float lo, float hi) {
#if __has_builtin(__builtin_amdgcn_cvt_pk_fp8_f32)
    int p = __builtin_amdgcn_cvt_pk_fp8_f32(lo, hi, 0, false);
    return (unsigned short)((unsigned int)p & 0xffffu);
#else
    return (unsigned short)(enc_fp8_sw(lo) | (enc_fp8_sw(hi) << 8));
#endif
}
template<bool HI>
__device__ __forceinline__ floatx2 cvt2(unsigned int w) {
#if __has_builtin(__builtin_amdgcn_cvt_pk_f32_fp8)
    return __builtin_amdgcn_cvt_pk_f32_fp8((int)w, HI);
#else
    unsigned int g = HI ? (w >> 16) : (w & 0xffffu);
    floatx2 r; r[0] = dec_fp8_sw(g & 0xffu); r[1] = dec_fp8_sw((g >> 8) & 0xffu);
    return r;
#endif
}

// ---------------------------------------------------------------------------
// Kernel 1: detect edge_index dtype (sampled). flag=1 -> int32.
// ---------------------------------------------------------------------------
__global__ void detect_dtype_kernel(const int* __restrict__ ei32, int* __restrict__ flag) {
    int i = threadIdx.x;
    int found = 0;
    for (int w = 2 * i + 1; w < 8192; w += 512)
        found |= (ei32[w] != 0);
    if (found) atomicOr(flag, 1);
}

// ---------------------------------------------------------------------------
// Kernel 1b: per-(class,block) histogram of dst. Block b counts its edge chunk
// into LDS, writes hist[c*2048+b]. Mapping MUST match bin_kernel exactly.
// ---------------------------------------------------------------------------
__global__ __launch_bounds__(256) void hist_kernel(
    const void* __restrict__ ei, const int* __restrict__ flag,
    int* __restrict__ hist) {
    __shared__ int lh[NCLS];
    bool is64 = (*flag == 0);
    int tid = threadIdx.x;
    if (tid < NCLS) lh[tid] = 0;
    __syncthreads();
    int i = blockIdx.x * 256 + tid;
    int stride = 256 * EDGE_GRID;
    for (int e = i; e < N_EDGES; e += stride) {
        int d = is64 ? (int)((const long long*)ei)[N_EDGES + e]
                     : ((const int*)ei)[N_EDGES + e];
        atomicAdd(&lh[(unsigned)d / CLS_RANGE], 1);
    }
    __syncthreads();
    if (tid < NCLS) hist[tid * EDGE_GRID + blockIdx.x] = lh[tid];
}

// ---------------------------------------------------------------------------
// Kernel 1c: exclusive scan of hist[16384] -> pos (region bases). Class c's
// partition = [pos[c*2048], pos[(c+1)*2048]); block b's region within it
// starts at pos[c*2048+b]. Exact by construction.
// ---------------------------------------------------------------------------
__global__ __launch_bounds__(1024) void hist_scan_kernel(
    const int* __restrict__ hist, int* __restrict__ pos) {
    __shared__ int part[1024];
    int tid = threadIdx.x;
    int b0 = tid * 16;
    int s = 0;
    for (int j = b0; j < b0 + 16; ++j) s += hist[j];
    part[tid] = s;
    __syncthreads();
    int val = s;
    #pragma unroll
    for (int off = 1; off < 1024; off <<= 1) {
        int t = (tid >= off) ? part[tid - off] : 0;
        __syncthreads();
        val += t;
        part[tid] = val;
        __syncthreads();
    }
    int run = val - s;
    for (int j = b0; j < b0 + 16; ++j) { pos[j] = run; run += hist[j]; }
    if (tid == 1023) pos[NHIST] = N_EDGES;
}

// ---------------------------------------------------------------------------
// Kernel 1d: bin edges by dst-class. Same edge mapping as hist_kernel; block
// appends into its reserved regions via LDS cursors (no global atomics).
// ---------------------------------------------------------------------------
__global__ __launch_bounds__(256) void bin_kernel(
    const void* __restrict__ ei, const int* __restrict__ flag,
    const int* __restrict__ pos, uint2* __restrict__ binned) {
    __shared__ int lcur[NCLS];
    bool is64 = (*flag == 0);
    int tid = threadIdx.x;
    if (tid < NCLS) lcur[tid] = pos[tid * EDGE_GRID + blockIdx.x];
    __syncthreads();
    int i = blockIdx.x * 256 + tid;
    int stride = 256 * EDGE_GRID;
    for (int e = i; e < N_EDGES; e += stride) {
        int s, d;
        if (is64) {
            s = (int)((const long long*)ei)[e];
            d = (int)((const long long*)ei)[N_EDGES + e];
        } else {
            s = ((const int*)ei)[e];
            d = ((const int*)ei)[N_EDGES + e];
        }
        int c = (unsigned)d / CLS_RANGE;
        int p = atomicAdd(&lcur[c], 1);
        binned[p] = make_uint2((unsigned)s, (unsigned)d);
    }
}

// ---------------------------------------------------------------------------
// Kernel 2: degree count from binned partition c (3.2MB read + 50KB atomic
// window, both resident in XCD-c's L2).
// ---------------------------------------------------------------------------
__global__ __launch_bounds__(256) void degree_kernel(
    const uint2* __restrict__ binned, const int* __restrict__ pos,
    int* __restrict__ deg) {
    int c = blockIdx.x & (NCLS - 1);
    int lo = pos[c * EDGE_GRID];
    int hi = (c == NCLS - 1) ? N_EDGES : pos[(c + 1) * EDGE_GRID];
    int i = lo + (blockIdx.x >> 3) * 256 + threadIdx.x;
    int stride = 256 * (EDGE_GRID / NCLS);
    for (int e = i; e < hi; e += stride)
        atomicAdd(&deg[binned[e].y], 1);
}

// ---------------------------------------------------------------------------
// Kernels 3a/3b/3c: hierarchical exclusive scan -> offs/cursor/isq/dinv
// ---------------------------------------------------------------------------
__global__ __launch_bounds__(256) void scan1_kernel(const int* __restrict__ deg,
                                                    int* __restrict__ bsum) {
    __shared__ int red[256];
    int tid = threadIdx.x;
    int i = blockIdx.x * 256 + tid;
    int v = (i < N_NODES) ? deg[i] : 0;
    red[tid] = v;
    __syncthreads();
    #pragma unroll
    for (int off = 128; off > 0; off >>= 1) {
        if (tid < off) red[tid] += red[tid + off];
        __syncthreads();
    }
    if (tid == 0) bsum[blockIdx.x] = red[0];
}

__global__ __launch_bounds__(512) void scan2_kernel(int* __restrict__ bsum) {
    __shared__ int sh[512];
    int tid = threadIdx.x;
    int v = (tid < NB_SCAN) ? bsum[tid] : 0;
    sh[tid] = v;
    __syncthreads();
    int val = v;
    #pragma unroll
    for (int off = 1; off < 512; off <<= 1) {
        int t = (tid >= off) ? sh[tid - off] : 0;
        __syncthreads();
        val += t;
        sh[tid] = val;
        __syncthreads();
    }
    if (tid < NB_SCAN) bsum[tid] = val - v;   // exclusive block prefix
}

__global__ __launch_bounds__(256) void scan3_kernel(const int* __restrict__ deg,
                                                    const int* __restrict__ bsum,
                                                    int* __restrict__ offs,
                                                    int* __restrict__ cursor,
                                                    float* __restrict__ isq,
                                                    float* __restrict__ dinv) {
    __shared__ int sh[256];
    int tid = threadIdx.x;
    int i = blockIdx.x * 256 + tid;
    int d = (i < N_NODES) ? deg[i] : 0;
    sh[tid] = d;
    __syncthreads();
    int val = d;
    #pragma unroll
    for (int off = 1; off < 256; off <<= 1) {
        int t = (tid >= off) ? sh[tid - off] : 0;
        __syncthreads();
        val += t;
        sh[tid] = val;
        __syncthreads();
    }
    int ex = bsum[blockIdx.x] + val - d;      // exclusive prefix for node i
    if (i < N_NODES) {
        offs[i] = ex;
        cursor[i] = ex;
        float dr = (float)(d + 1);
        isq[i] = rsqrtf(dr);
        dinv[i] = 1.0f / dr;
    }
    if (i == 0) offs[N_NODES] = N_EDGES;
}

// ---------------------------------------------------------------------------
// Kernel 4: CSR fill from binned partition c. Read stream 3.2MB + cursor 50KB
// + csr window 1.6MB all fit XCD-c's L2 -> lines written back once, full.
// ---------------------------------------------------------------------------
__global__ __launch_bounds__(256) void fill_kernel(
    const uint2* __restrict__ binned, const int* __restrict__ pos,
    int* __restrict__ cursor, unsigned int* __restrict__ csr) {
    int c = blockIdx.x & (NCLS - 1);
    int lo = pos[c * EDGE_GRID];
    int hi = (c == NCLS - 1) ? N_EDGES : pos[(c + 1) * EDGE_GRID];
    int i = lo + (blockIdx.x >> 3) * 256 + threadIdx.x;
    int stride = 256 * (EDGE_GRID / NCLS);
    for (int e = i; e < hi; e += stride) {
        uint2 r = binned[e];
        int p = atomicAdd(&cursor[(int)r.y], 1);
        csr[p] = r.x;
    }
}

// ---------------------------------------------------------------------------
// Kernel 5: prep weights: Wt[c][k] = bf16(W[k][c]), bias vector biasAll[192].
// ---------------------------------------------------------------------------
__global__ void prep_w_kernel(const float* __restrict__ Whp, const float* __restrict__ bhp,
                              const float* __restrict__ Wlp, const float* __restrict__ blp,
                              const float* __restrict__ Wi,  const float* __restrict__ bi,
                              __hip_bfloat16* __restrict__ Wt, float* __restrict__ biasAll) {
    int c = blockIdx.x;      // 0..191
    int k = threadIdx.x;     // 0..255
    const float* W = (c < 64) ? Whp : (c < 128) ? Wlp : Wi;
    int cl = c & 63;
    Wt[c * 256 + k] = __float2bfloat16(W[k * 64 + cl]);
    if (k == 0) {
        const float* b = (c < 64) ? bhp : (c < 128) ? blp : bi;
        biasAll[c] = b[cl];
    }
}

// ---------------------------------------------------------------------------
// Kernel 6: bf16 MFMA GEMM (unchanged). Writes hq = fp8x2{hp,lp}*isq
// (gather table), hg = bf16x2{hp,lp} unscaled (self), hgi = bf16 i-branch.
// ---------------------------------------------------------------------------
__global__ __launch_bounds__(256) void gemm_kernel(
    const float* __restrict__ x,
    const __hip_bfloat16* __restrict__ Wt,
    const float* __restrict__ biasAll,
    const float* __restrict__ isq,
    unsigned short* __restrict__ hq,
    unsigned int* __restrict__ hg, unsigned short* __restrict__ hgi) {

    __shared__ __align__(16) __hip_bfloat16 xs[64][264];

    const int tid = threadIdx.x;
    const int node0 = blockIdx.x * 64;
    const int w = tid >> 6;
    const int lane = tid & 63;
    const int cl = lane & 15;
    const int kh = lane >> 4;

    short8 B[3][8];
    #pragma unroll
    for (int s = 0; s < 3; ++s) {
        const __hip_bfloat16* wp = Wt + (16 * w + 64 * s + cl) * 256 + kh * 8;
        #pragma unroll
        for (int ks = 0; ks < 8; ++ks)
            B[s][ks] = *(const short8*)(wp + ks * 32);
    }

    #pragma unroll
    for (int j = 0; j < 16; ++j) {
        int f = j * 1024 + tid * 4;
        int rr = f >> 8, cc = f & 255;
        float4v v = {0.f, 0.f, 0.f, 0.f};
        int node = node0 + rr;
        if (node < N_NODES)
            v = *(const float4v*)(x + (size_t)node * 256 + cc);
        __hip_bfloat16 b0 = __float2bfloat16(v.x), b1 = __float2bfloat16(v.y);
        __hip_bfloat16 b2 = __float2bfloat16(v.z), b3 = __float2bfloat16(v.w);
        unsigned int lo = (unsigned int)*(unsigned short*)&b0 | ((unsigned int)*(unsigned short*)&b1 << 16);
        unsigned int hi = (unsigned int)*(unsigned short*)&b2 | ((unsigned int)*(unsigned short*)&b3 << 16);
        unsigned int* dst = (unsigned int*)&xs[rr][cc];
        dst[0] = lo; dst[1] = hi;
    }
    __syncthreads();

    float4v acc[4][3];
    #pragma unroll
    for (int rt = 0; rt < 4; ++rt)
        #pragma unroll
        for (int s = 0; s < 3; ++s)
            acc[rt][s] = (float4v){0.f, 0.f, 0.f, 0.f};

    const char* xbase = (const char*)&xs[0][0];
    #pragma unroll
    for (int ks = 0; ks < 8; ++ks) {
        short8 A[4];
        #pragma unroll
        for (int rt = 0; rt < 4; ++rt)
            A[rt] = *(const short8*)(xbase + (size_t)(rt * 16 + cl) * 528 + ks * 64 + kh * 16);
        #pragma unroll
        for (int rt = 0; rt < 4; ++rt)
            #pragma unroll
            for (int s = 0; s < 3; ++s)
                acc[rt][s] = __builtin_amdgcn_mfma_f32_16x16x32_bf16(A[rt], B[s][ks], acc[rt][s], 0, 0, 0);
    }

    const int c0 = 16 * w + cl;
    const float bias_hp = biasAll[c0];
    const float bias_lp = biasAll[c0 + 64];
    const float bias_i  = biasAll[c0 + 128];

    #pragma unroll
    for (int rt = 0; rt < 4; ++rt) {
        #pragma unroll
        for (int r = 0; r < 4; ++r) {
            int node = node0 + rt * 16 + kh * 4 + r;
            if (node >= N_NODES) continue;
            float sq = isq[node];
            float vhp = acc[rt][0][r] + bias_hp;
            float vlp = acc[rt][1][r] + bias_lp;
            float vi  = acc[rt][2][r] + bias_i;
            hq[(size_t)node * 64 + c0] = pack_fp8x2(vhp * sq, vlp * sq);
            __hip_bfloat16 bh = __float2bfloat16(vhp);
            __hip_bfloat16 bl = __float2bfloat16(vlp);
            __hip_bfloat16 bb = __float2bfloat16(vi);
            hg[(size_t)node * 64 + c0] =
                (unsigned int)*(unsigned short*)&bh | ((unsigned int)*(unsigned short*)&bl << 16);
            hgi[(size_t)node * 64 + c0] = *(unsigned short*)&bb;
        }
    }
}

// ---------------------------------------------------------------------------
// Kernel 7: fused aggregation + gates + log_softmax, v2 (unchanged).
// ---------------------------------------------------------------------------
__device__ __forceinline__ float wave_sum(float x) {
    #pragma unroll
    for (int off = 32; off > 0; off >>= 1) x += __shfl_xor(x, off);
    return x;
}
__device__ __forceinline__ float wave_max(float x) {
    #pragma unroll
    for (int off = 32; off > 0; off >>= 1) x = fmaxf(x, __shfl_xor(x, off));
    return x;
}

__global__ __launch_bounds__(256) void agg_kernel(
    const unsigned short* __restrict__ hq,
    const unsigned int* __restrict__ hg,
    const unsigned short* __restrict__ hgi,
    const int* __restrict__ offs,
    const unsigned int* __restrict__ csr,
    const float* __restrict__ isq,
    const float* __restrict__ dinv,
    const float* __restrict__ w_gh, const float* __restrict__ b_gh,
    const float* __restrict__ w_gl, const float* __restrict__ b_gl,
    const float* __restrict__ w_gi, const float* __restrict__ b_gi,
    float* __restrict__ out) {
    __shared__ float2 xf[4][8 * 65];          // per-wave transpose scratch

    int wid = threadIdx.x >> 6;
    int v = blockIdx.x * 4 + wid;
    int lane = threadIdx.x & 63;
    if (v >= N_NODES) return;

    int start = offs[v], end = offs[v + 1];
    const int slot = lane >> 3;               // neighbor slot 0..7
    const int oct  = lane & 7;                // feature octet 0..7
    const char* hqB = (const char*)hq;

    float ahp[8], alp[8];
    #pragma unroll
    for (int j = 0; j < 8; ++j) { ahp[j] = 0.f; alp[j] = 0.f; }

    for (int j0 = start; j0 < end; j0 += 64) {
        int m = end - j0; if (m > 64) m = 64;
        unsigned int uu = 0;
        if (lane < m) uu = csr[j0 + lane];
        for (int k0 = 0; k0 < m; k0 += 8) {
            int idx = k0 + slot;
            bool valid = idx < m;
            int idxc = valid ? idx : (m - 1);
            unsigned int u = __shfl(uu, idxc);
            uint4v g = *(const uint4v*)(hqB + (size_t)u * 128 + oct * 16);
            unsigned int zm = valid ? 0xffffffffu : 0u;
            #pragma unroll
            for (int dd = 0; dd < 4; ++dd) {
                unsigned int wv = g[dd] & zm;
                floatx2 e0 = cvt2<false>(wv);
                floatx2 e1 = cvt2<true>(wv);
                ahp[2 * dd]     += e0[0]; alp[2 * dd]     += e0[1];
                ahp[2 * dd + 1] += e1[0]; alp[2 * dd + 1] += e1[1];
            }
        }
    }

    #pragma unroll
    for (int j = 0; j < 8; ++j)
        xf[wid][slot * 65 + oct * 8 + j] = make_float2(ahp[j], alp[j]);
    float acc_hp = 0.f, acc_lp = 0.f;
    #pragma unroll
    for (int s = 0; s < 8; ++s) {
        float2 t = xf[wid][s * 65 + lane];
        acc_hp += t.x; acc_lp += t.y;
    }

    float isqv = isq[v];
    float agg_hp = acc_hp * isqv;
    float agg_lp = acc_lp * isqv;

    unsigned int gv = hg[(size_t)v * 64 + lane];
    float hhp = __uint_as_float(gv << 16);
    float hlp = __uint_as_float(gv & 0xffff0000u);
    float hi  = __uint_as_float((unsigned int)hgi[(size_t)v * 64 + lane] << 16);

    float dv = dinv[v];
    float Hhp = fmaxf(hhp - (agg_hp + dv * hhp), 0.f);
    float Hlp = fmaxf(agg_lp + dv * hlp, 0.f);
    float Hi  = fmaxf(hi, 0.f);

    float sh = wave_sum(Hhp * w_gh[lane]) + b_gh[0];
    float sl = wave_sum(Hlp * w_gl[lane]) + b_gl[0];
    float si = wave_sum(Hi  * w_gi[lane]) + b_gi[0];

    float o = sh * Hhp + sl * Hlp + si * Hi;
    float mx = wave_max(o);
    float se = wave_sum(expf(o - mx));
    out[(size_t)v * 64 + lane] = o - mx - logf(se);
}

// ---------------------------------------------------------------------------
static inline size_t align256(size_t v) { return (v + 255) & ~(size_t)255; }

extern "C" void kernel_launch(void* const* d_in, const int* in_sizes, int n_in,
                              void* d_out, int out_size, void* d_ws, size_t ws_size,
                              hipStream_t stream) {
    const float* x    = (const float*)d_in[0];
    const void*  ei   = d_in[1];
    const float* Whp  = (const float*)d_in[2];
    const float* bhp  = (const float*)d_in[3];
    const float* Wlp  = (const float*)d_in[4];
    const float* blp  = (const float*)d_in[5];
    const float* Wi   = (const float*)d_in[6];
    const float* bi   = (const float*)d_in[7];
    const float* w_gh = (const float*)d_in[8];
    const float* b_gh = (const float*)d_in[9];
    const float* w_gl = (const float*)d_in[10];
    const float* b_gl = (const float*)d_in[11];
    const float* w_gi = (const float*)d_in[12];
    const float* b_gi = (const float*)d_in[13];
    float* out = (float*)d_out;

    const int N = N_NODES, E = N_EDGES;

    // workspace layout (256B-aligned regions)
    char* base = (char*)d_ws;
    size_t off = 0;
    int* flag = (int*)(base + off);            off = align256(off + sizeof(int));
    int* deg = (int*)(base + off);             off = align256(off + (size_t)N * 4);
    size_t zero_end = off;                     // memset covers [0, zero_end)
    int* offs = (int*)(base + off);            off = align256(off + (size_t)(N + 1) * 4);
    int* cursor = (int*)(base + off);          off = align256(off + (size_t)N * 4);
    float* isq = (float*)(base + off);         off = align256(off + (size_t)N * 4);
    float* dinv = (float*)(base + off);        off = align256(off + (size_t)N * 4);
    int* bsum = (int*)(base + off);            off = align256(off + (size_t)NB_SCAN * 4);
    int* hist = (int*)(base + off);            off = align256(off + (size_t)NHIST * 4);
    int* pos = (int*)(base + off);             off = align256(off + (size_t)(NHIST + 1) * 4);
    uint2* binned = (uint2*)(base + off);      off = align256(off + (size_t)E * 8);
    unsigned int* csr = (unsigned int*)(base + off); off = align256(off + (size_t)E * 4);
    float* biasAll = (float*)(base + off);     off = align256(off + 192 * 4);
    __hip_bfloat16* Wt = (__hip_bfloat16*)(base + off); off = align256(off + 192 * 256 * 2);
    unsigned short* hq = (unsigned short*)(base + off); off = align256(off + (size_t)N * 64 * 2);
    unsigned int* hg = (unsigned int*)(base + off);   off = align256(off + (size_t)N * 64 * 4);
    unsigned short* hgi = (unsigned short*)(base + off); off = align256(off + (size_t)N * 64 * 2);

    // zero flag + deg
    (void)hipMemsetAsync(base, 0, zero_end, stream);

    detect_dtype_kernel<<<1, 256, 0, stream>>>((const int*)ei, flag);
    hist_kernel<<<EDGE_GRID, 256, 0, stream>>>(ei, flag, hist);
    hist_scan_kernel<<<1, 1024, 0, stream>>>(hist, pos);
    bin_kernel<<<EDGE_GRID, 256, 0, stream>>>(ei, flag, pos, binned);
    degree_kernel<<<EDGE_GRID, 256, 0, stream>>>(binned, pos, deg);
    scan1_kernel<<<NB_SCAN, 256, 0, stream>>>(deg, bsum);
    scan2_kernel<<<1, 512, 0, stream>>>(bsum);
    scan3_kernel<<<NB_SCAN, 256, 0, stream>>>(deg, bsum, offs, cursor, isq, dinv);
    fill_kernel<<<EDGE_GRID, 256, 0, stream>>>(binned, pos, cursor, csr);
    prep_w_kernel<<<192, 256, 0, stream>>>(Whp, bhp, Wlp, blp, Wi, bi, Wt, biasAll);
    gemm_kernel<<<(N + 63) / 64, 256, 0, stream>>>(x, Wt, biasAll, isq, hq, hg, hgi);
    agg_kernel<<<(N + 3) / 4, 256, 0, stream>>>(hq, hg, hgi, offs, csr, isq, dinv,
                                                w_gh, b_gh, w_gl, b_gl, w_gi, b_gi, out);
}

// Round 13
// 220.943 us; speedup vs baseline: 11.0957x; 1.9826x over previous
//
#include <hip/hip_runtime.h>
#include <hip/hip_bf16.h>

#define N_NODES 100000
#define N_EDGES 3200000
#define IN_DIM  256
#define OUT_DIM 64
#define NBUK2   512
#define BRANGE  196                       // 512*196 = 100352 >= 100000
#define BINBLK  256                       // blocks in hist/bin (mapping MUST match)
#define CHUNK   (N_EDGES / BINBLK)        // 12500
#define HTOT    (NBUK2 * BINBLK)          // 131072
#define CAP     12288                     // LDS staging entries (48KB); mean 6250

typedef __attribute__((ext_vector_type(8))) short short8;
typedef __attribute__((ext_vector_type(4))) float float4v;
typedef __attribute__((ext_vector_type(2))) float floatx2;
typedef __attribute__((ext_vector_type(4))) unsigned int uint4v;

// ---------------------------------------------------------------------------
// fp8 e4m3 pack/unpack (HW cvt on gfx950, software fallback)
// ---------------------------------------------------------------------------
__device__ __forceinline__ unsigned int enc_fp8_sw(float v) {
    unsigned int u = __float_as_uint(v);
    unsigned int s = (u >> 24) & 0x80u;
    unsigned int mag = u & 0x7fffffffu;
    unsigned int q;
    if (mag >= 0x43e00000u) q = 0x7e;
    else if (mag < 0x3c800000u) {
        float av = __uint_as_float(mag);
        q = (unsigned int)(av * 512.0f + 0.5f);
    } else {
        unsigned int mr = mag + 0x00080000u;
        unsigned int e = (mr >> 23) - 127 + 7;
        unsigned int m = (mr >> 20) & 7;
        q = (e << 3) | m;
        if (q > 0x7e) q = 0x7e;
    }
    return s | q;
}
__device__ __forceinline__ float dec_fp8_sw(unsigned int b) {
    unsigned int s = (b & 0x80u) << 24;
    unsigned int e = (b >> 3) & 15u, m = b & 7u;
    float f = (e == 0) ? (float)m * 0.001953125f
                       : __uint_as_float(((e + 120u) << 23) | (m << 20));
    return __uint_as_float(__float_as_uint(f) | s);
}

__device__ __forceinline__ unsigned short pack_fp8x2(float lo, float hi) {
#if __has_builtin(__builtin_amdgcn_cvt_pk_fp8_f32)
    int p = __builtin_amdgcn_cvt_pk_fp8_f32(lo, hi, 0, false);
    return (unsigned short)((unsigned int)p & 0xffffu);
#else
    return (unsigned short)(enc_fp8_sw(lo) | (enc_fp8_sw(hi) << 8));
#endif
}
template<bool HI>
__device__ __forceinline__ floatx2 cvt2(unsigned int w) {
#if __has_builtin(__builtin_amdgcn_cvt_pk_f32_fp8)
    return __builtin_amdgcn_cvt_pk_f32_fp8((int)w, HI);
#else
    unsigned int g = HI ? (w >> 16) : (w & 0xffffu);
    floatx2 r; r[0] = dec_fp8_sw(g & 0xffu); r[1] = dec_fp8_sw((g >> 8) & 0xffu);
    return r;
#endif
}

// ---------------------------------------------------------------------------
// Kernel 1: detect edge_index dtype (sampled). flag=1 -> int32.
// ---------------------------------------------------------------------------
__global__ void detect_dtype_kernel(const int* __restrict__ ei32, int* __restrict__ flag) {
    int i = threadIdx.x;
    int found = 0;
    for (int w = 2 * i + 1; w < 8192; w += 512)
        found |= (ei32[w] != 0);
    if (found) atomicOr(flag, 1);
}

// ---------------------------------------------------------------------------
// Kernel 2a: per-(bucket,block) histogram of dst. Block blk counts its edge
// chunk [blk*CHUNK,(blk+1)*CHUNK) into a 512-entry LDS histogram, then writes
// hist[b*BINBLK+blk] (bucket-major). Mapping must match bin_kernel exactly.
// ---------------------------------------------------------------------------
__global__ __launch_bounds__(256) void hist_kernel(
    const void* __restrict__ ei, const int* __restrict__ flag,
    int* __restrict__ hist) {
    __shared__ int lh[NBUK2];
    bool is64 = (*flag == 0);
    int tid = threadIdx.x;
    for (int b = tid; b < NBUK2; b += 256) lh[b] = 0;
    __syncthreads();
    int e0 = blockIdx.x * CHUNK, e1 = e0 + CHUNK;
    for (int e = e0 + tid; e < e1; e += 256) {
        int d = is64 ? (int)((const long long*)ei)[N_EDGES + e]
                     : ((const int*)ei)[N_EDGES + e];
        atomicAdd(&lh[(unsigned)d / BRANGE], 1);
    }
    __syncthreads();
    for (int b = tid; b < NBUK2; b += 256) hist[b * BINBLK + blockIdx.x] = lh[b];
}

// ---------------------------------------------------------------------------
// Kernels 2b/2c/2d: exclusive scan of hist[HTOT] -> pos. pos[b*BINBLK] is both
// the binned-region base AND the CSR offset of bucket b's first node.
// ---------------------------------------------------------------------------
__global__ __launch_bounds__(256) void hscan1_kernel(const int* __restrict__ hist,
                                                     int* __restrict__ hb) {
    __shared__ int red[256];
    int tid = threadIdx.x;
    red[tid] = hist[blockIdx.x * 256 + tid];
    __syncthreads();
    #pragma unroll
    for (int off = 128; off > 0; off >>= 1) {
        if (tid < off) red[tid] += red[tid + off];
        __syncthreads();
    }
    if (tid == 0) hb[blockIdx.x] = red[0];
}

__global__ __launch_bounds__(512) void hscan2_kernel(int* __restrict__ hb) {
    __shared__ int sh[512];
    int tid = threadIdx.x;
    int v = hb[tid];
    sh[tid] = v;
    __syncthreads();
    int val = v;
    #pragma unroll
    for (int off = 1; off < 512; off <<= 1) {
        int t = (tid >= off) ? sh[tid - off] : 0;
        __syncthreads();
        val += t;
        sh[tid] = val;
        __syncthreads();
    }
    hb[tid] = val - v;                    // exclusive block prefix
}

__global__ __launch_bounds__(256) void hscan3_kernel(const int* __restrict__ hist,
                                                     const int* __restrict__ hb,
                                                     int* __restrict__ pos) {
    __shared__ int sh[256];
    int tid = threadIdx.x;
    int i = blockIdx.x * 256 + tid;
    int v = hist[i];
    sh[tid] = v;
    __syncthreads();
    int val = v;
    #pragma unroll
    for (int off = 1; off < 256; off <<= 1) {
        int t = (tid >= off) ? sh[tid - off] : 0;
        __syncthreads();
        val += t;
        sh[tid] = val;
        __syncthreads();
    }
    pos[i] = hb[blockIdx.x] + val - v;
    if (i == HTOT - 1) pos[HTOT] = N_EDGES;
}

// ---------------------------------------------------------------------------
// Kernel 2e: bin edges by dst-bucket. Same chunk mapping as hist_kernel; each
// block appends into its exactly-reserved regions via LDS cursors only.
// ---------------------------------------------------------------------------
__global__ __launch_bounds__(256) void bin_kernel(
    const void* __restrict__ ei, const int* __restrict__ flag,
    const int* __restrict__ pos, uint2* __restrict__ binned) {
    __shared__ int lcur[NBUK2];
    bool is64 = (*flag == 0);
    int tid = threadIdx.x;
    for (int b = tid; b < NBUK2; b += 256) lcur[b] = pos[b * BINBLK + blockIdx.x];
    __syncthreads();
    int e0 = blockIdx.x * CHUNK, e1 = e0 + CHUNK;
    for (int e = e0 + tid; e < e1; e += 256) {
        int s, d;
        if (is64) {
            s = (int)((const long long*)ei)[e];
            d = (int)((const long long*)ei)[N_EDGES + e];
        } else {
            s = ((const int*)ei)[e];
            d = ((const int*)ei)[N_EDGES + e];
        }
        int p = atomicAdd(&lcur[(unsigned)d / BRANGE], 1);
        binned[p] = make_uint2((unsigned)s, (unsigned)d);
    }
}

// ---------------------------------------------------------------------------
// Kernel 3: per-bucket CSR build fully in LDS. Block b: read bucket edges
// (L2-hot), count 196 local degrees, LDS scan, scatter src into LDS staging,
// stream staging out SEQUENTIALLY. Also writes offs/isq/dinv (no global scan,
// no cursor, no degree kernel). Fallback path for >CAP buckets (never expected
// for uniform input; +76 sigma).
// ---------------------------------------------------------------------------
__global__ __launch_bounds__(256) void fill_kernel(
    const uint2* __restrict__ binned, const int* __restrict__ pos,
    unsigned int* __restrict__ csr, int* __restrict__ offs,
    float* __restrict__ isq, float* __restrict__ dinv) {
    __shared__ int ldeg[BRANGE];
    __shared__ int lpre[256];
    __shared__ int lcur[BRANGE];
    __shared__ unsigned int stag[CAP];

    int b = blockIdx.x;
    int ns = b * BRANGE;
    if (ns >= N_NODES) return;
    int ne = ns + BRANGE; if (ne > N_NODES) ne = N_NODES;
    int nn = ne - ns;
    int lo = pos[b * BINBLK];
    int hi = pos[(b + 1) * BINBLK];
    int nb = hi - lo;
    int tid = threadIdx.x;

    for (int i = tid; i < nn; i += 256) ldeg[i] = 0;
    __syncthreads();
    for (int e = lo + tid; e < hi; e += 256)
        atomicAdd(&ldeg[binned[e].y - ns], 1);
    __syncthreads();

    int d = (tid < nn) ? ldeg[tid] : 0;
    lpre[tid] = d;
    __syncthreads();
    int val = d;
    #pragma unroll
    for (int off = 1; off < 256; off <<= 1) {
        int t = (tid >= off) ? lpre[tid - off] : 0;
        __syncthreads();
        val += t;
        lpre[tid] = val;
        __syncthreads();
    }
    int ex = val - d;                     // local exclusive prefix
    if (tid < nn) {
        lcur[tid] = ex;
        offs[ns + tid] = lo + ex;
        float dr = (float)(d + 1);
        isq[ns + tid] = rsqrtf(dr);
        dinv[ns + tid] = 1.0f / dr;
    }
    if (tid == 0 && ne == N_NODES) offs[N_NODES] = hi;   // == N_EDGES
    __syncthreads();

    if (nb <= CAP) {
        for (int e = lo + tid; e < hi; e += 256) {
            uint2 r = binned[e];
            int p = atomicAdd(&lcur[r.y - ns], 1);
            stag[p] = r.x;
        }
        __syncthreads();
        for (int j = tid; j < nb; j += 256)
            csr[lo + j] = stag[j];
    } else {
        for (int e = lo + tid; e < hi; e += 256) {
            uint2 r = binned[e];
            int p = atomicAdd(&lcur[r.y - ns], 1);
            csr[lo + p] = r.x;
        }
    }
}

// ---------------------------------------------------------------------------
// Kernel 5: prep weights: Wt[c][k] = bf16(W[k][c]), bias vector biasAll[192].
// ---------------------------------------------------------------------------
__global__ void prep_w_kernel(const float* __restrict__ Whp, const float* __restrict__ bhp,
                              const float* __restrict__ Wlp, const float* __restrict__ blp,
                              const float* __restrict__ Wi,  const float* __restrict__ bi,
                              __hip_bfloat16* __restrict__ Wt, float* __restrict__ biasAll) {
    int c = blockIdx.x;      // 0..191
    int k = threadIdx.x;     // 0..255
    const float* W = (c < 64) ? Whp : (c < 128) ? Wlp : Wi;
    int cl = c & 63;
    Wt[c * 256 + k] = __float2bfloat16(W[k * 64 + cl]);
    if (k == 0) {
        const float* b = (c < 64) ? bhp : (c < 128) ? blp : bi;
        biasAll[c] = b[cl];
    }
}

// ---------------------------------------------------------------------------
// Kernel 6: bf16 MFMA GEMM (unchanged). Writes hq = fp8x2{hp,lp}*isq
// (gather table), hg = bf16x2{hp,lp} unscaled (self), hgi = bf16 i-branch.
// ---------------------------------------------------------------------------
__global__ __launch_bounds__(256) void gemm_kernel(
    const float* __restrict__ x,
    const __hip_bfloat16* __restrict__ Wt,
    const float* __restrict__ biasAll,
    const float* __restrict__ isq,
    unsigned short* __restrict__ hq,
    unsigned int* __restrict__ hg, unsigned short* __restrict__ hgi) {

    __shared__ __align__(16) __hip_bfloat16 xs[64][264];

    const int tid = threadIdx.x;
    const int node0 = blockIdx.x * 64;
    const int w = tid >> 6;
    const int lane = tid & 63;
    const int cl = lane & 15;
    const int kh = lane >> 4;

    short8 B[3][8];
    #pragma unroll
    for (int s = 0; s < 3; ++s) {
        const __hip_bfloat16* wp = Wt + (16 * w + 64 * s + cl) * 256 + kh * 8;
        #pragma unroll
        for (int ks = 0; ks < 8; ++ks)
            B[s][ks] = *(const short8*)(wp + ks * 32);
    }

    #pragma unroll
    for (int j = 0; j < 16; ++j) {
        int f = j * 1024 + tid * 4;
        int rr = f >> 8, cc = f & 255;
        float4v v = {0.f, 0.f, 0.f, 0.f};
        int node = node0 + rr;
        if (node < N_NODES)
            v = *(const float4v*)(x + (size_t)node * 256 + cc);
        __hip_bfloat16 b0 = __float2bfloat16(v.x), b1 = __float2bfloat16(v.y);
        __hip_bfloat16 b2 = __float2bfloat16(v.z), b3 = __float2bfloat16(v.w);
        unsigned int lo = (unsigned int)*(unsigned short*)&b0 | ((unsigned int)*(unsigned short*)&b1 << 16);
        unsigned int hi = (unsigned int)*(unsigned short*)&b2 | ((unsigned int)*(unsigned short*)&b3 << 16);
        unsigned int* dst = (unsigned int*)&xs[rr][cc];
        dst[0] = lo; dst[1] = hi;
    }
    __syncthreads();

    float4v acc[4][3];
    #pragma unroll
    for (int rt = 0; rt < 4; ++rt)
        #pragma unroll
        for (int s = 0; s < 3; ++s)
            acc[rt][s] = (float4v){0.f, 0.f, 0.f, 0.f};

    const char* xbase = (const char*)&xs[0][0];
    #pragma unroll
    for (int ks = 0; ks < 8; ++ks) {
        short8 A[4];
        #pragma unroll
        for (int rt = 0; rt < 4; ++rt)
            A[rt] = *(const short8*)(xbase + (size_t)(rt * 16 + cl) * 528 + ks * 64 + kh * 16);
        #pragma unroll
        for (int rt = 0; rt < 4; ++rt)
            #pragma unroll
            for (int s = 0; s < 3; ++s)
                acc[rt][s] = __builtin_amdgcn_mfma_f32_16x16x32_bf16(A[rt], B[s][ks], acc[rt][s], 0, 0, 0);
    }

    const int c0 = 16 * w + cl;
    const float bias_hp = biasAll[c0];
    const float bias_lp = biasAll[c0 + 64];
    const float bias_i  = biasAll[c0 + 128];

    #pragma unroll
    for (int rt = 0; rt < 4; ++rt) {
        #pragma unroll
        for (int r = 0; r < 4; ++r) {
            int node = node0 + rt * 16 + kh * 4 + r;
            if (node >= N_NODES) continue;
            float sq = isq[node];
            float vhp = acc[rt][0][r] + bias_hp;
            float vlp = acc[rt][1][r] + bias_lp;
            float vi  = acc[rt][2][r] + bias_i;
            hq[(size_t)node * 64 + c0] = pack_fp8x2(vhp * sq, vlp * sq);
            __hip_bfloat16 bh = __float2bfloat16(vhp);
            __hip_bfloat16 bl = __float2bfloat16(vlp);
            __hip_bfloat16 bb = __float2bfloat16(vi);
            hg[(size_t)node * 64 + c0] =
                (unsigned int)*(unsigned short*)&bh | ((unsigned int)*(unsigned short*)&bl << 16);
            hgi[(size_t)node * 64 + c0] = *(unsigned short*)&bb;
        }
    }
}

// ---------------------------------------------------------------------------
// Kernel 7: fused aggregation + gates + log_softmax, v2 (unchanged).
// ---------------------------------------------------------------------------
__device__ __forceinline__ float wave_sum(float x) {
    #pragma unroll
    for (int off = 32; off > 0; off >>= 1) x += __shfl_xor(x, off);
    return x;
}
__device__ __forceinline__ float wave_max(float x) {
    #pragma unroll
    for (int off = 32; off > 0; off >>= 1) x = fmaxf(x, __shfl_xor(x, off));
    return x;
}

__global__ __launch_bounds__(256) void agg_kernel(
    const unsigned short* __restrict__ hq,
    const unsigned int* __restrict__ hg,
    const unsigned short* __restrict__ hgi,
    const int* __restrict__ offs,
    const unsigned int* __restrict__ csr,
    const float* __restrict__ isq,
    const float* __restrict__ dinv,
    const float* __restrict__ w_gh, const float* __restrict__ b_gh,
    const float* __restrict__ w_gl, const float* __restrict__ b_gl,
    const float* __restrict__ w_gi, const float* __restrict__ b_gi,
    float* __restrict__ out) {
    __shared__ float2 xf[4][8 * 65];          // per-wave transpose scratch

    int wid = threadIdx.x >> 6;
    int v = blockIdx.x * 4 + wid;
    int lane = threadIdx.x & 63;
    if (v >= N_NODES) return;

    int start = offs[v], end = offs[v + 1];
    const int slot = lane >> 3;               // neighbor slot 0..7
    const int oct  = lane & 7;                // feature octet 0..7
    const char* hqB = (const char*)hq;

    float ahp[8], alp[8];
    #pragma unroll
    for (int j = 0; j < 8; ++j) { ahp[j] = 0.f; alp[j] = 0.f; }

    for (int j0 = start; j0 < end; j0 += 64) {
        int m = end - j0; if (m > 64) m = 64;
        unsigned int uu = 0;
        if (lane < m) uu = csr[j0 + lane];
        for (int k0 = 0; k0 < m; k0 += 8) {
            int idx = k0 + slot;
            bool valid = idx < m;
            int idxc = valid ? idx : (m - 1);
            unsigned int u = __shfl(uu, idxc);
            uint4v g = *(const uint4v*)(hqB + (size_t)u * 128 + oct * 16);
            unsigned int zm = valid ? 0xffffffffu : 0u;
            #pragma unroll
            for (int dd = 0; dd < 4; ++dd) {
                unsigned int wv = g[dd] & zm;
                floatx2 e0 = cvt2<false>(wv);
                floatx2 e1 = cvt2<true>(wv);
                ahp[2 * dd]     += e0[0]; alp[2 * dd]     += e0[1];
                ahp[2 * dd + 1] += e1[0]; alp[2 * dd + 1] += e1[1];
            }
        }
    }

    #pragma unroll
    for (int j = 0; j < 8; ++j)
        xf[wid][slot * 65 + oct * 8 + j] = make_float2(ahp[j], alp[j]);
    float acc_hp = 0.f, acc_lp = 0.f;
    #pragma unroll
    for (int s = 0; s < 8; ++s) {
        float2 t = xf[wid][s * 65 + lane];
        acc_hp += t.x; acc_lp += t.y;
    }

    float isqv = isq[v];
    float agg_hp = acc_hp * isqv;
    float agg_lp = acc_lp * isqv;

    unsigned int gv = hg[(size_t)v * 64 + lane];
    float hhp = __uint_as_float(gv << 16);
    float hlp = __uint_as_float(gv & 0xffff0000u);
    float hi  = __uint_as_float((unsigned int)hgi[(size_t)v * 64 + lane] << 16);

    float dv = dinv[v];
    float Hhp = fmaxf(hhp - (agg_hp + dv * hhp), 0.f);
    float Hlp = fmaxf(agg_lp + dv * hlp, 0.f);
    float Hi  = fmaxf(hi, 0.f);

    float sh = wave_sum(Hhp * w_gh[lane]) + b_gh[0];
    float sl = wave_sum(Hlp * w_gl[lane]) + b_gl[0];
    float si = wave_sum(Hi  * w_gi[lane]) + b_gi[0];

    float o = sh * Hhp + sl * Hlp + si * Hi;
    float mx = wave_max(o);
    float se = wave_sum(expf(o - mx));
    out[(size_t)v * 64 + lane] = o - mx - logf(se);
}

// ---------------------------------------------------------------------------
static inline size_t align256(size_t v) { return (v + 255) & ~(size_t)255; }

extern "C" void kernel_launch(void* const* d_in, const int* in_sizes, int n_in,
                              void* d_out, int out_size, void* d_ws, size_t ws_size,
                              hipStream_t stream) {
    const float* x    = (const float*)d_in[0];
    const void*  ei   = d_in[1];
    const float* Whp  = (const float*)d_in[2];
    const float* bhp  = (const float*)d_in[3];
    const float* Wlp  = (const float*)d_in[4];
    const float* blp  = (const float*)d_in[5];
    const float* Wi   = (const float*)d_in[6];
    const float* bi   = (const float*)d_in[7];
    const float* w_gh = (const float*)d_in[8];
    const float* b_gh = (const float*)d_in[9];
    const float* w_gl = (const float*)d_in[10];
    const float* b_gl = (const float*)d_in[11];
    const float* w_gi = (const float*)d_in[12];
    const float* b_gi = (const float*)d_in[13];
    float* out = (float*)d_out;

    const int N = N_NODES, E = N_EDGES;

    // workspace layout (256B-aligned regions)
    char* base = (char*)d_ws;
    size_t off = 0;
    int* flag = (int*)(base + off);            off = align256(off + sizeof(int));
    size_t zero_end = off;                     // memset covers [0, zero_end)
    int* offs = (int*)(base + off);            off = align256(off + (size_t)(N + 1) * 4);
    float* isq = (float*)(base + off);         off = align256(off + (size_t)N * 4);
    float* dinv = (float*)(base + off);        off = align256(off + (size_t)N * 4);
    int* hist = (int*)(base + off);            off = align256(off + (size_t)HTOT * 4);
    int* hb = (int*)(base + off);              off = align256(off + 512 * 4);
    int* pos = (int*)(base + off);             off = align256(off + (size_t)(HTOT + 1) * 4);
    uint2* binned = (uint2*)(base + off);      off = align256(off + (size_t)E * 8);
    unsigned int* csr = (unsigned int*)(base + off); off = align256(off + (size_t)E * 4);
    float* biasAll = (float*)(base + off);     off = align256(off + 192 * 4);
    __hip_bfloat16* Wt = (__hip_bfloat16*)(base + off); off = align256(off + 192 * 256 * 2);
    unsigned short* hq = (unsigned short*)(base + off); off = align256(off + (size_t)N * 64 * 2);
    unsigned int* hg = (unsigned int*)(base + off);   off = align256(off + (size_t)N * 64 * 4);
    unsigned short* hgi = (unsigned short*)(base + off); off = align256(off + (size_t)N * 64 * 2);

    // zero flag
    (void)hipMemsetAsync(base, 0, zero_end, stream);

    detect_dtype_kernel<<<1, 256, 0, stream>>>((const int*)ei, flag);
    hist_kernel<<<BINBLK, 256, 0, stream>>>(ei, flag, hist);
    hscan1_kernel<<<HTOT / 256, 256, 0, stream>>>(hist, hb);
    hscan2_kernel<<<1, 512, 0, stream>>>(hb);
    hscan3_kernel<<<HTOT / 256, 256, 0, stream>>>(hist, hb, pos);
    bin_kernel<<<BINBLK, 256, 0, stream>>>(ei, flag, pos, binned);
    fill_kernel<<<NBUK2, 256, 0, stream>>>(binned, pos, csr, offs, isq, dinv);
    prep_w_kernel<<<192, 256, 0, stream>>>(Whp, bhp, Wlp, blp, Wi, bi, Wt, biasAll);
    gemm_kernel<<<(N + 63) / 64, 256, 0, stream>>>(x, Wt, biasAll, isq, hq, hg, hgi);
    agg_kernel<<<(N + 3) / 4, 256, 0, stream>>>(hq, hg, hgi, offs, csr, isq, dinv,
                                                w_gh, b_gh, w_gl, b_gl, w_gi, b_gi, out);
}